// Round 4
// baseline (1084.084 us; speedup 1.0000x reference)
//
#include <hip/hip_runtime.h>
#include <cstdint>
#include <cstddef>

#define EMB 256
#define NN 20000
#define NE 200000
#define NE2 400000

typedef unsigned short ushort_t;
typedef __attribute__((ext_vector_type(8))) short bf16x8;
typedef __attribute__((ext_vector_type(4))) float f32x4;

// ---------------------------------------------------------------------------
// bf16 helpers (RNE)
// ---------------------------------------------------------------------------
__device__ __forceinline__ ushort_t f2bf(float f) {
    unsigned u = __float_as_uint(f);
    u += 0x7FFFu + ((u >> 16) & 1u);
    return (ushort_t)(u >> 16);
}
__device__ __forceinline__ float bf2f(ushort_t u) {
    return __uint_as_float(((unsigned)u) << 16);
}

// async global->LDS, 16B per lane. LDS dest = wave-uniform base + lane*16.
__device__ __forceinline__ void async_cp16(const ushort_t* g, ushort_t* l) {
    __builtin_amdgcn_global_load_lds(
        (const __attribute__((address_space(1))) unsigned int*)g,
        (__attribute__((address_space(3))) unsigned int*)l,
        16, 0, 0);
}

// ---------------------------------------------------------------------------
// XCD-pair swizzle for col-split GEMMs: dispatch round-robins blocks over 8
// XCDs; map flat bid so the two col-halves of a row-block are 8 slots apart
// (same XCD, temporally adjacent) -> 2nd A-tile read hits that XCD's L2.
// Bijective for any T (tail handled separately).
// ---------------------------------------------------------------------------
__device__ __forceinline__ void pc_map(int bid, int T, int& p, int& colblk) {
    int Tf = T & ~15;
    if (bid < Tf) {
        p = (bid >> 4) * 8 + (bid & 7);
        colblk = (bid >> 3) & 1;
    } else {
        int rem = bid - Tf;
        int nr = (T - Tf) >> 1;
        p = (T >> 1) - nr + rem % nr;
        colblk = rem / nr;
    }
}

// ---------------------------------------------------------------------------
// Threefry2x32, partitionable mode: bits(e) = o0^o1 of threefry((0,42),(0,e))
// ---------------------------------------------------------------------------
__device__ __forceinline__ unsigned rotl32(unsigned v, int d) {
    return (v << d) | (v >> (32 - d));
}
__device__ __forceinline__ void threefry2x32(unsigned k0, unsigned k1,
                                             unsigned x0, unsigned x1,
                                             unsigned& o0, unsigned& o1) {
    unsigned k2 = k0 ^ k1 ^ 0x1BD11BDAu;
    x0 += k0; x1 += k1;
#define TF_R(r) { x0 += x1; x1 = rotl32(x1, (r)); x1 ^= x0; }
    TF_R(13) TF_R(15) TF_R(26) TF_R(6)
    x0 += k1; x1 += k2 + 1u;
    TF_R(17) TF_R(29) TF_R(16) TF_R(24)
    x0 += k2; x1 += k0 + 2u;
    TF_R(13) TF_R(15) TF_R(26) TF_R(6)
    x0 += k0; x1 += k1 + 3u;
    TF_R(17) TF_R(29) TF_R(16) TF_R(24)
    x0 += k1; x1 += k2 + 4u;
    TF_R(13) TF_R(15) TF_R(26) TF_R(6)
    x0 += k2; x1 += k0 + 5u;
#undef TF_R
    o0 = x0; o1 = x1;
}

// ---------------------------------------------------------------------------
// CSR build
// ---------------------------------------------------------------------------
__global__ void deg_kernel(const int* __restrict__ src, const int* __restrict__ dst,
                           int* __restrict__ deg) {
    int i = blockIdx.x * blockDim.x + threadIdx.x;
    if (i < NE2) {
        int n = (i < NE) ? dst[i] : src[i - NE];
        atomicAdd(&deg[n], 1);
    }
}

__global__ void prefix_kernel(const int* __restrict__ deg, int* __restrict__ row_start,
                              int* __restrict__ cursor) {
    __shared__ int sums[1024];
    int t = threadIdx.x;
    const int CH = (NN + 1023) / 1024;
    int lo = t * CH, hi = lo + CH;
    if (hi > NN) hi = NN;
    if (lo > NN) lo = NN;
    int s = 0;
    for (int n = lo; n < hi; n++) s += deg[n];
    sums[t] = s;
    __syncthreads();
    for (int off = 1; off < 1024; off <<= 1) {
        int v = (t >= off) ? sums[t - off] : 0;
        __syncthreads();
        sums[t] += v;
        __syncthreads();
    }
    int run = (t == 0) ? 0 : sums[t - 1];
    for (int n = lo; n < hi; n++) {
        row_start[n] = run;
        cursor[n] = run;
        run += deg[n];
    }
    if (t == 1023) row_start[NN] = sums[1023];
}

__global__ void scatter_kernel(const int* __restrict__ src, const int* __restrict__ dst,
                               int* __restrict__ cursor, int* __restrict__ elist) {
    int i = blockIdx.x * blockDim.x + threadIdx.x;
    if (i < NE2) {
        int n = (i < NE) ? dst[i] : src[i - NE];
        int pos = atomicAdd(&cursor[n], 1);
        elist[pos] = i;
    }
}

// ---------------------------------------------------------------------------
// fp32 -> bf16 bulk convert, two arrays in one launch
// ---------------------------------------------------------------------------
__global__ void conv2_kernel(const float* __restrict__ a, ushort_t* __restrict__ oa, int na8,
                             const float* __restrict__ b, ushort_t* __restrict__ ob, int nb8) {
    int i = blockIdx.x * 256 + threadIdx.x;
    const float* p;
    ushort_t* o;
    if (i < na8) { p = a + (size_t)i * 8; o = oa + (size_t)i * 8; }
    else {
        int j = i - na8;
        if (j >= nb8) return;
        p = b + (size_t)j * 8; o = ob + (size_t)j * 8;
    }
    float4 u = *(const float4*)p;
    float4 v = *(const float4*)(p + 4);
    union { ushort_t s[8]; uint4 w; } r;
    r.s[0] = f2bf(u.x); r.s[1] = f2bf(u.y); r.s[2] = f2bf(u.z); r.s[3] = f2bf(u.w);
    r.s[4] = f2bf(v.x); r.s[5] = f2bf(v.y); r.s[6] = f2bf(v.z); r.s[7] = f2bf(v.w);
    *(uint4*)o = r.w;
}

// ---------------------------------------------------------------------------
// All weight transposes in one launch. dst[n*stride + koff + k] = bf16(src[k*256+n])
// ---------------------------------------------------------------------------
struct TD { const float* src; ushort_t* dst; int stride, koff, kr; };
struct TA { TD d[8]; };

__global__ void transpose_all_kernel(TA ta) {
    TD t = ta.d[blockIdx.y];
    int k = blockIdx.x;
    if (k >= t.kr) return;
    int n = threadIdx.x;
    t.dst[(size_t)n * t.stride + t.koff + k] = f2bf(t.src[(size_t)k * 256 + n]);
}

// ---------------------------------------------------------------------------
// Fused reverse-edge MLP: ea_rev = relu(ea @ W1 + b1) @ W2 + b2
//  One block per 128 edges; h (128x256) never leaves the block.
//  Phase 1: m97-style K-loop (K=256), acc[4][8] (full 256 cols).
//  Pack h to bf16 in regs (64 u32/lane), then phase 2 consumes h through a
//  34 KB LDS half-buffer (two 128-col chunks written by their owner waves).
//  LDS 59 KB, ~230 regs -> 2 blocks/CU. Only HBM stream: ea read + out write.
// ---------------------------------------------------------------------------
__global__ __launch_bounds__(256, 2) void rev_fused_kernel(
        const ushort_t* __restrict__ ea_bf,
        const ushort_t* __restrict__ Wt1, const float* __restrict__ b1,
        const ushort_t* __restrict__ Wt2, const float* __restrict__ b2,
        ushort_t* __restrict__ ea_rev) {
    __shared__ ushort_t As[128 * 32];    // 8 KB
    __shared__ ushort_t Bs[256 * 32];    // 16 KB
    __shared__ ushort_t Hl[128 * 136];   // 34 KB, h half-chunk [row][k], pad 136

    int tid = threadIdx.x;
    int lane = tid & 63, wave = tid >> 6;
    int wr = wave >> 1, wc = wave & 1;
    int quad = lane >> 4, col_l = lane & 15;
    int p = blockIdx.x;

    f32x4 acc[4][8];
#pragma unroll
    for (int mt = 0; mt < 4; mt++)
#pragma unroll
        for (int nt = 0; nt < 8; nt++) acc[mt][nt] = (f32x4)0.f;

    // ---- phase 1: h = relu(ea @ W1 + b1), K = 256 ----
    for (int k0 = 0; k0 < 256; k0 += 32) {
        __syncthreads();
#pragma unroll
        for (int j = 0; j < 2; j++) {        // A tile 128x32
            int flat = tid + 256 * j;
            int row = flat >> 2, ch = flat & 3;
            int grow = p * 128 + row;
            if (grow >= NE) grow = NE - 1;
            async_cp16(ea_bf + (size_t)grow * 256 + k0 + ch * 8,
                       As + (wave * 64 + 256 * j) * 8);
        }
#pragma unroll
        for (int j = 0; j < 4; j++) {        // B tile 256x32
            int flat = tid + 256 * j;
            int n = flat >> 2, ch = flat & 3;
            async_cp16(Wt1 + (size_t)n * 256 + k0 + ch * 8,
                       Bs + (wave * 64 + 256 * j) * 8);
        }
        __syncthreads();
        bf16x8 a[4], b[8];
#pragma unroll
        for (int mt = 0; mt < 4; mt++)
            a[mt] = *(const bf16x8*)(As + (wr * 64 + mt * 16 + col_l) * 32 + quad * 8);
#pragma unroll
        for (int nt = 0; nt < 8; nt++)
            b[nt] = *(const bf16x8*)(Bs + (wc * 128 + nt * 16 + col_l) * 32 + quad * 8);
#pragma unroll
        for (int mt = 0; mt < 4; mt++)
#pragma unroll
            for (int nt = 0; nt < 8; nt++)
                acc[mt][nt] = __builtin_amdgcn_mfma_f32_16x16x32_bf16(
                    a[mt], b[nt], acc[mt][nt], 0, 0, 0);
    }

    // ---- bias + relu + pack h to bf16 (acc dies here; 64 u32 regs live) ----
    unsigned hpk[4][8][2];
#pragma unroll
    for (int mt = 0; mt < 4; mt++)
#pragma unroll
        for (int nt = 0; nt < 8; nt++) {
            float bb = b1[wc * 128 + nt * 16 + col_l];
#pragma unroll
            for (int j = 0; j < 2; j++) {
                float f0 = fmaxf(acc[mt][nt][2 * j] + bb, 0.f);
                float f1 = fmaxf(acc[mt][nt][2 * j + 1] + bb, 0.f);
                hpk[mt][nt][j] = (unsigned)f2bf(f0) | ((unsigned)f2bf(f1) << 16);
            }
        }

    // ---- phase 2: out = h @ W2 + b2, K = 256 in two 128-col chunks ----
    f32x4 acc2[4][8];
#pragma unroll
    for (int mt = 0; mt < 4; mt++)
#pragma unroll
        for (int nt = 0; nt < 8; nt++) {
            float bb = b2[wc * 128 + nt * 16 + col_l];
            acc2[mt][nt] = (f32x4)0.f;
            if (mt == 0) {  // add bias once (per col, all rows): fold into acc2[0]? No:
            }
            acc2[mt][nt][0] = (mt == 0) ? 0.f : 0.f;  // keep zero; bias added at store
            (void)bb;
        }

    for (int hc = 0; hc < 2; hc++) {
        __syncthreads();   // prior readers of Hl done
        if (wc == hc) {
            // owner waves write their h col-half: rows wr*64..+64, cols 0..127
#pragma unroll
            for (int mt = 0; mt < 4; mt++)
#pragma unroll
                for (int nt = 0; nt < 8; nt++)
#pragma unroll
                    for (int j = 0; j < 2; j++) {
                        int row = wr * 64 + mt * 16 + quad * 4 + 2 * j;
                        int cc = nt * 16 + col_l;
                        unsigned u = hpk[mt][nt][j];
                        Hl[row * 136 + cc] = (ushort_t)u;
                        Hl[(row + 1) * 136 + cc] = (ushort_t)(u >> 16);
                    }
        }
        for (int kk = 0; kk < 4; kk++) {
            __syncthreads();   // Bs readers done (also makes Hl writes visible)
#pragma unroll
            for (int j = 0; j < 4; j++) {   // B tile: Wt2 rows 0..255, k chunk
                int flat = tid + 256 * j;
                int n = flat >> 2, ch = flat & 3;
                async_cp16(Wt2 + (size_t)n * 256 + hc * 128 + kk * 32 + ch * 8,
                           Bs + (wave * 64 + 256 * j) * 8);
            }
            __syncthreads();   // drain
            bf16x8 a[4], b[8];
#pragma unroll
            for (int mt = 0; mt < 4; mt++)
                a[mt] = *(const bf16x8*)(Hl + (wr * 64 + mt * 16 + col_l) * 136
                                         + kk * 32 + quad * 8);
#pragma unroll
            for (int nt = 0; nt < 8; nt++)
                b[nt] = *(const bf16x8*)(Bs + (wc * 128 + nt * 16 + col_l) * 32 + quad * 8);
#pragma unroll
            for (int mt = 0; mt < 4; mt++)
#pragma unroll
                for (int nt = 0; nt < 8; nt++)
                    acc2[mt][nt] = __builtin_amdgcn_mfma_f32_16x16x32_bf16(
                        a[mt], b[nt], acc2[mt][nt], 0, 0, 0);
        }
    }

    // ---- store ea_rev (bf16, + b2) ----
#pragma unroll
    for (int mt = 0; mt < 4; mt++)
#pragma unroll
        for (int nt = 0; nt < 8; nt++) {
            int colg = wc * 128 + nt * 16 + col_l;
            float bb = b2[colg];
#pragma unroll
            for (int r = 0; r < 4; r++) {
                int rg = p * 128 + wr * 64 + mt * 16 + quad * 4 + r;
                if (rg < NE)
                    ea_rev[(size_t)rg * 256 + colg] = f2bf(acc2[mt][nt][r] + bb);
            }
        }
}

// ---------------------------------------------------------------------------
// m97-shape bf16 MFMA GEMM: C[M x 256] = A[M x KTOT] @ B[KTOT x 256]
//  Tile 128 rows x 128 cols, col-half via XCD-pair swizzled blockIdx.
//  4 waves 2x2, acc[4][4] = 64 AGPR, single LDS buffer, 2-barrier K-loop,
//  3 blocks/CU.
//  A seg0 (k<256): bf16 (A0F32=false) or fp32 (A0F32=true, reg-staged+cvt).
//  A seg1 (k>=256, KTOT==512): bf16 at A1/rsA1.
//  Bt/out selected by blockIdx.y (Bt2/out2) for paired launches.
//  EPI: 0 fp32 store, 2 bf16+bias, 3 bf16+bias+relu,
//       4 pred-head PARTIAL (col-half sums; finalize adds + b2 + noise)
// ---------------------------------------------------------------------------
template <int KTOT, int EPI, bool A0F32>
__global__ __launch_bounds__(256, 3) void mfma_gemm(
        const void* __restrict__ A0v, int rsA0,
        const ushort_t* __restrict__ A1, int rsA1,
        const ushort_t* __restrict__ Bt, const ushort_t* __restrict__ Bt2,
        const float* __restrict__ bias,
        void* __restrict__ out, void* __restrict__ out2, int rsOut, int M,
        const int* __restrict__ srcp, const int* __restrict__ dstp,
        const float* __restrict__ Hs, const float* __restrict__ Hd,
        const float* __restrict__ w2) {
    __shared__ ushort_t As[128 * 32];   // 8 KB
    __shared__ ushort_t Bs[128 * 32];   // 8 KB
    __shared__ float red[128];

    int tid = threadIdx.x;
    int lane = tid & 63;
    int wave = tid >> 6;
    int wr = wave >> 1;
    int wc = wave & 1;
    int quad = lane >> 4;
    int col_l = lane & 15;
    int p, colblk;
    pc_map(blockIdx.x, gridDim.x, p, colblk);

    const ushort_t* Bsel = blockIdx.y ? Bt2 : Bt;
    void* Osel = blockIdx.y ? out2 : out;

    f32x4 acc[4][4];
#pragma unroll
    for (int mt = 0; mt < 4; mt++)
#pragma unroll
        for (int nt = 0; nt < 4; nt++) acc[mt][nt] = (f32x4)0.f;

    for (int k0 = 0; k0 < KTOT; k0 += 32) {
        __syncthreads();   // prior reads of As/Bs complete before overwrite
        // B first: async loads fly while the fp32-A path waits on its loads
#pragma unroll
        for (int j = 0; j < 2; j++) {
            int flat = tid + 256 * j;
            int n = flat >> 2, ch = flat & 3;
            const ushort_t* gp = Bsel + (size_t)(colblk * 128 + n) * KTOT + k0 + ch * 8;
            async_cp16(gp, Bs + ((wave * 64 + 256 * j) * 8));
        }
        bool seg1 = (KTOT == 512) && (k0 >= 256);
        if (A0F32 && !seg1) {
            // fp32 A: load 32B/thread, convert, ds_write 16B (same LDS layout)
#pragma unroll
            for (int j = 0; j < 2; j++) {
                int flat = tid + 256 * j;
                int row = flat >> 2, ch = flat & 3;
                int grow = p * 128 + row;
                if (grow >= M) grow = M - 1;
                const float* gp = (const float*)A0v + (size_t)grow * rsA0 + k0 + ch * 8;
                float4 u = *(const float4*)gp;
                float4 v = *(const float4*)(gp + 4);
                union { ushort_t s[8]; uint4 w; } r;
                r.s[0] = f2bf(u.x); r.s[1] = f2bf(u.y); r.s[2] = f2bf(u.z); r.s[3] = f2bf(u.w);
                r.s[4] = f2bf(v.x); r.s[5] = f2bf(v.y); r.s[6] = f2bf(v.z); r.s[7] = f2bf(v.w);
                *(uint4*)(As + (size_t)flat * 8) = r.w;
            }
        } else {
            const ushort_t* abase;
            int rs, koffs;
            if (KTOT == 512 && k0 >= 256) { abase = A1; rs = rsA1; koffs = k0 - 256; }
            else { abase = (const ushort_t*)A0v; rs = rsA0; koffs = k0; }
#pragma unroll
            for (int j = 0; j < 2; j++) {
                int flat = tid + 256 * j;
                int row = flat >> 2, ch = flat & 3;
                int grow = p * 128 + row;
                if (grow >= M) grow = M - 1;
                const ushort_t* gp = abase + (size_t)grow * rs + koffs + ch * 8;
                async_cp16(gp, As + ((wave * 64 + 256 * j) * 8));
            }
        }
        __syncthreads();   // drain: loads landed in LDS

        bf16x8 a[4], b[4];
#pragma unroll
        for (int mt = 0; mt < 4; mt++)
            a[mt] = *(const bf16x8*)(As + (wr * 64 + mt * 16 + col_l) * 32 + quad * 8);
#pragma unroll
        for (int nt = 0; nt < 4; nt++)
            b[nt] = *(const bf16x8*)(Bs + (wc * 64 + nt * 16 + col_l) * 32 + quad * 8);
#pragma unroll
        for (int mt = 0; mt < 4; mt++)
#pragma unroll
            for (int nt = 0; nt < 4; nt++)
                acc[mt][nt] = __builtin_amdgcn_mfma_f32_16x16x32_bf16(
                    a[mt], b[nt], acc[mt][nt], 0, 0, 0);
    }

    if (EPI == 4) {
        // pred-head partial epilogue (this column half only)
        __syncthreads();
        if (tid < 128) red[tid] = 0.f;
        __syncthreads();
        float b1c[4], w2c[4];
#pragma unroll
        for (int nt = 0; nt < 4; nt++) {
            int col = colblk * 128 + wc * 64 + nt * 16 + col_l;
            b1c[nt] = bias[col];
            w2c[nt] = w2[col];
        }
#pragma unroll
        for (int mt = 0; mt < 4; mt++) {
#pragma unroll
            for (int r = 0; r < 4; r++) {
                int lrow = wr * 64 + mt * 16 + quad * 4 + r;
                int e = p * 128 + lrow;
                int ec = e < M ? e : M - 1;
                int s = srcp[ec], d = dstp[ec];
                const float* hsr = Hs + (size_t)s * 256;
                const float* hdr = Hd + (size_t)d * 256;
                float part = 0.f;
#pragma unroll
                for (int nt = 0; nt < 4; nt++) {
                    int col = colblk * 128 + wc * 64 + nt * 16 + col_l;
                    part += fmaxf(acc[mt][nt][r] + hsr[col] + hdr[col] + b1c[nt], 0.f)
                            * w2c[nt];
                }
#pragma unroll
                for (int m = 8; m > 0; m >>= 1) part += __shfl_xor(part, m, 64);
                if (col_l == 0) atomicAdd(&red[lrow], part);
            }
        }
        __syncthreads();
        if (tid < 128) {
            int e = p * 128 + tid;
            if (e < M) {
                float* tgt = colblk ? (float*)out2 : (float*)out;
                tgt[e] = red[tid];
            }
        }
        return;
    }

    float bs[4];
    if (EPI >= 2) {
#pragma unroll
        for (int nt = 0; nt < 4; nt++)
            bs[nt] = bias[colblk * 128 + wc * 64 + nt * 16 + col_l];
    }
#pragma unroll
    for (int mt = 0; mt < 4; mt++) {
#pragma unroll
        for (int nt = 0; nt < 4; nt++) {
            int colg = colblk * 128 + wc * 64 + nt * 16 + col_l;
#pragma unroll
            for (int r = 0; r < 4; r++) {
                int rg = p * 128 + wr * 64 + mt * 16 + quad * 4 + r;
                if (rg < M) {
                    float v = acc[mt][nt][r];
                    if (EPI >= 2) v += bs[nt];
                    if (EPI == 3) v = fmaxf(v, 0.f);
                    if (EPI == 0)
                        ((float*)Osel)[(size_t)rg * rsOut + colg] = v;
                    else
                        ((ushort_t*)Osel)[(size_t)rg * rsOut + colg] = f2bf(v);
                }
            }
        }
    }
}

// ---------------------------------------------------------------------------
// Finalize pred head: logit = part0 + part1 + b2; sampled = sigmoid(logit+noise)
// ---------------------------------------------------------------------------
__global__ void finalize_kernel(float* __restrict__ out, const float* __restrict__ part1,
                                const float* __restrict__ b2v, float* __restrict__ out_s) {
    int e = blockIdx.x * blockDim.x + threadIdx.x;
    if (e >= NE) return;
    float logit = out[e] + part1[e] + b2v[0];
    out[e] = logit;
    unsigned y0, y1;
    threefry2x32(0u, 42u, 0u, (unsigned)e, y0, y1);
    unsigned bits = y0 ^ y1;
    float f = __uint_as_float((bits >> 9) | 0x3F800000u) - 1.0f;
    float u = fmaxf(1e-10f, f + 1e-10f);
    float noise = logf(u) - logf(1.0f - u);
    out_s[e] = 1.0f / (1.0f + expf(-(logit + noise)));
}

// ---------------------------------------------------------------------------
// Mean aggregation over bf16 features. One wave per node; lane owns 4 cols.
// ---------------------------------------------------------------------------
__global__ __launch_bounds__(64) void agg_bf_kernel(
        const ushort_t* __restrict__ xin, int rsx,
        const ushort_t* __restrict__ eaf, const ushort_t* __restrict__ ear,
        const int* __restrict__ src, const int* __restrict__ dst,
        const int* __restrict__ row_start, const int* __restrict__ elist,
        const int* __restrict__ deg, ushort_t* __restrict__ agg) {
    int n = blockIdx.x;
    int c = threadIdx.x * 4;
    float ax = 0.f, ay = 0.f, az = 0.f, aw = 0.f;
    int beg = row_start[n], end = row_start[n + 1];
    for (int p = beg; p < end; p++) {
        int i = elist[p];
        const ushort_t* xr;
        const ushort_t* er;
        if (i < NE) { xr = xin + (size_t)src[i] * rsx; er = eaf + (size_t)i * 256; }
        else { int j = i - NE; xr = xin + (size_t)dst[j] * rsx; er = ear + (size_t)j * 256; }
        ushort4 xv = *(const ushort4*)(xr + c);
        ushort4 ev = *(const ushort4*)(er + c);
        ax += bf2f(xv.x) + bf2f(ev.x);
        ay += bf2f(xv.y) + bf2f(ev.y);
        az += bf2f(xv.z) + bf2f(ev.z);
        aw += bf2f(xv.w) + bf2f(ev.w);
    }
    float d = fmaxf((float)deg[n], 1.0f);
    ushort4 o;
    o.x = f2bf(ax / d); o.y = f2bf(ay / d); o.z = f2bf(az / d); o.w = f2bf(aw / d);
    *(ushort4*)(agg + (size_t)n * 256 + c) = o;
}

// ---------------------------------------------------------------------------
extern "C" void kernel_launch(void* const* d_in, const int* in_sizes, int n_in,
                              void* d_out, int out_size, void* d_ws, size_t ws_size,
                              hipStream_t stream) {
    const float* x        = (const float*)d_in[0];
    const float* ea       = (const float*)d_in[1];
    const float* qemb     = (const float*)d_in[2];
    const int*   eidx     = (const int*)d_in[3];
    const float* W_rev1   = (const float*)d_in[4];
    const float* b_rev1   = (const float*)d_in[5];
    const float* W_rev2   = (const float*)d_in[6];
    const float* b_rev2   = (const float*)d_in[7];
    const float* W_sage1  = (const float*)d_in[8];
    const float* b_sage1  = (const float*)d_in[9];
    const float* W_sage2  = (const float*)d_in[10];
    const float* b_sage2  = (const float*)d_in[11];
    const float* W_pred1  = (const float*)d_in[12];
    const float* b_pred1  = (const float*)d_in[13];
    const float* W_pred2  = (const float*)d_in[14];
    const float* b_pred2  = (const float*)d_in[15];
    float* out = (float*)d_out;

    const int* src = eidx;
    const int* dst = eidx + NE;

    // ---- workspace layout ----
    char* w = (char*)d_ws;
    ushort_t* ea_bf  = (ushort_t*)w; w += (size_t)NE * 256 * 2;   // 102.4 MB
    ushort_t* ea_rev_bf = (ushort_t*)w; w += (size_t)NE * 256 * 2;// 102.4 MB
    ushort_t* x_bf   = (ushort_t*)w; w += (size_t)NN * 256 * 2;
    ushort_t* H      = (ushort_t*)w; w += (size_t)NN * 512 * 2;   // [h1|h2]
    ushort_t* agg_bf = (ushort_t*)w; w += (size_t)NN * 256 * 2;
    float*    Hsrc   = (float*)w;    w += (size_t)NN * 256 * 4;
    float*    Hdst   = (float*)w;    w += (size_t)NN * 256 * 4;
    float*    part1  = (float*)w;    w += (size_t)NE * 4;         // pred col-half 1 partial
    ushort_t* Wt_rev1  = (ushort_t*)w; w += 256 * 256 * 2;
    ushort_t* Wt_rev2  = (ushort_t*)w; w += 256 * 256 * 2;
    ushort_t* Wt_sage1 = (ushort_t*)w; w += 256 * 512 * 2;
    ushort_t* Wt_sage2 = (ushort_t*)w; w += 256 * 512 * 2;
    ushort_t* Wt_src   = (ushort_t*)w; w += 256 * 512 * 2;
    ushort_t* Wt_dst   = (ushort_t*)w; w += 256 * 512 * 2;
    ushort_t* Wt_edge  = (ushort_t*)w; w += 256 * 512 * 2;
    int* deg       = (int*)w; w += (size_t)NN * 4;
    int* row_start = (int*)w; w += (size_t)(NN + 1) * 4;
    int* cursor    = (int*)w; w += (size_t)NN * 4;
    int* elist     = (int*)w; w += (size_t)NE2 * 4;

    const int EB = (NE + 127) / 128;   // 1563 row-blocks
    const int NB = (NN + 127) / 128;   // 157 row-blocks

    // ---- CSR ----
    hipMemsetAsync(deg, 0, (size_t)NN * 4, stream);
    deg_kernel<<<(NE2 + 255) / 256, 256, 0, stream>>>(src, dst, deg);
    prefix_kernel<<<1, 1024, 0, stream>>>(deg, row_start, cursor);
    scatter_kernel<<<(NE2 + 255) / 256, 256, 0, stream>>>(src, dst, cursor, elist);

    // ---- all weight transposes, one launch ----
    TA ta;
    ta.d[0] = { W_rev1,  Wt_rev1,  256, 0,   256 };
    ta.d[1] = { W_rev2,  Wt_rev2,  256, 0,   256 };
    ta.d[2] = { W_sage1, Wt_sage1, 512, 0,   512 };
    ta.d[3] = { W_sage2, Wt_sage2, 512, 0,   512 };
    ta.d[4] = { W_pred1 + (size_t)256 * 256,  Wt_src,  512, 0,   512 };
    ta.d[5] = { W_pred1 + (size_t)1024 * 256, Wt_dst,  512, 0,   512 };
    ta.d[6] = { W_pred1,                      Wt_edge, 512, 0,   256 };
    ta.d[7] = { W_pred1 + (size_t)768 * 256,  Wt_edge, 512, 256, 256 };
    transpose_all_kernel<<<dim3(512, 8), 256, 0, stream>>>(ta);

    // ---- activations to bf16 (ea + x, one launch) ----
    conv2_kernel<<<((NE + NN) * 32 + 255) / 256, 256, 0, stream>>>(
        ea, ea_bf, NE * 32, x, x_bf, NN * 32);

    // ---- fused reverse-edge MLP (h never leaves the block) ----
    rev_fused_kernel<<<EB, 256, 0, stream>>>(
        ea_bf, Wt_rev1, b_rev1, Wt_rev2, b_rev2, ea_rev_bf);

    // ---- SAGE layer 1 ----
    agg_bf_kernel<<<NN, 64, 0, stream>>>(x_bf, 256, ea_bf, ea_rev_bf,
                                         src, dst, row_start, elist, deg, agg_bf);
    mfma_gemm<512, 3, false><<<NB * 2, 256, 0, stream>>>(
        x_bf, 256, agg_bf, 256, Wt_sage1, nullptr, b_sage1,
        H, nullptr, 512, NN, nullptr, nullptr, nullptr, nullptr, nullptr);

    // ---- SAGE layer 2 ----
    agg_bf_kernel<<<NN, 64, 0, stream>>>(H, 512, ea_bf, ea_rev_bf,
                                         src, dst, row_start, elist, deg, agg_bf);
    mfma_gemm<512, 3, false><<<NB * 2, 256, 0, stream>>>(
        H, 512, agg_bf, 256, Wt_sage2, nullptr, b_sage2,
        H + 256, nullptr, 512, NN, nullptr, nullptr, nullptr, nullptr, nullptr);

    // ---- node-side pred contributions: Hsrc & Hdst in one paired launch ----
    mfma_gemm<512, 0, false><<<dim3(NB * 2, 2), 256, 0, stream>>>(
        H, 512, H + 256, 512, Wt_src, Wt_dst, nullptr,
        Hsrc, Hdst, 256, NN, nullptr, nullptr, nullptr, nullptr, nullptr);

    // ---- edge GEMM + fused pred head partials (q read fp32, cvt in staging) ----
    mfma_gemm<512, 4, true><<<EB * 2, 256, 0, stream>>>(
        qemb, 256, ea_bf, 256, Wt_edge, nullptr, b_pred1,
        out, part1, 0, NE, src, dst, Hsrc, Hdst, W_pred2);

    // ---- finalize: add halves + b2, threefry noise, sigmoid ----
    finalize_kernel<<<(NE + 255) / 256, 256, 0, stream>>>(out, part1, b_pred2, out + NE);
}

// Round 5
// 983.147 us; speedup vs baseline: 1.1027x; 1.1027x over previous
//
#include <hip/hip_runtime.h>
#include <cstdint>
#include <cstddef>

#define EMB 256
#define NN 20000
#define NE 200000
#define NE2 400000

typedef unsigned short ushort_t;
typedef __attribute__((ext_vector_type(8))) short bf16x8;
typedef __attribute__((ext_vector_type(4))) float f32x4;

// ---------------------------------------------------------------------------
// bf16 helpers (RNE)
// ---------------------------------------------------------------------------
__device__ __forceinline__ ushort_t f2bf(float f) {
    unsigned u = __float_as_uint(f);
    u += 0x7FFFu + ((u >> 16) & 1u);
    return (ushort_t)(u >> 16);
}
__device__ __forceinline__ float bf2f(ushort_t u) {
    return __uint_as_float(((unsigned)u) << 16);
}

// async global->LDS, 16B per lane. LDS dest = wave-uniform base + lane*16.
__device__ __forceinline__ void async_cp16(const ushort_t* g, ushort_t* l) {
    __builtin_amdgcn_global_load_lds(
        (const __attribute__((address_space(1))) unsigned int*)g,
        (__attribute__((address_space(3))) unsigned int*)l,
        16, 0, 0);
}

// ---------------------------------------------------------------------------
// XCD-pair swizzle for col-split GEMMs: dispatch round-robins blocks over 8
// XCDs; map flat bid so the two col-halves of a row-block are 8 slots apart
// (same XCD, temporally adjacent) -> 2nd A-tile read hits that XCD's L2.
// Bijective for any T (tail handled separately). Verified-correct (round 4).
// ---------------------------------------------------------------------------
__device__ __forceinline__ void pc_map(int bid, int T, int& p, int& colblk) {
    int Tf = T & ~15;
    if (bid < Tf) {
        p = (bid >> 4) * 8 + (bid & 7);
        colblk = (bid >> 3) & 1;
    } else {
        int rem = bid - Tf;
        int nr = (T - Tf) >> 1;
        p = (T >> 1) - nr + rem % nr;
        colblk = rem / nr;
    }
}

// ---------------------------------------------------------------------------
// Threefry2x32, partitionable mode: bits(e) = o0^o1 of threefry((0,42),(0,e))
// ---------------------------------------------------------------------------
__device__ __forceinline__ unsigned rotl32(unsigned v, int d) {
    return (v << d) | (v >> (32 - d));
}
__device__ __forceinline__ void threefry2x32(unsigned k0, unsigned k1,
                                             unsigned x0, unsigned x1,
                                             unsigned& o0, unsigned& o1) {
    unsigned k2 = k0 ^ k1 ^ 0x1BD11BDAu;
    x0 += k0; x1 += k1;
#define TF_R(r) { x0 += x1; x1 = rotl32(x1, (r)); x1 ^= x0; }
    TF_R(13) TF_R(15) TF_R(26) TF_R(6)
    x0 += k1; x1 += k2 + 1u;
    TF_R(17) TF_R(29) TF_R(16) TF_R(24)
    x0 += k2; x1 += k0 + 2u;
    TF_R(13) TF_R(15) TF_R(26) TF_R(6)
    x0 += k0; x1 += k1 + 3u;
    TF_R(17) TF_R(29) TF_R(16) TF_R(24)
    x0 += k1; x1 += k2 + 4u;
    TF_R(13) TF_R(15) TF_R(26) TF_R(6)
    x0 += k2; x1 += k0 + 5u;
#undef TF_R
    o0 = x0; o1 = x1;
}

// ---------------------------------------------------------------------------
// CSR build
// ---------------------------------------------------------------------------
__global__ void deg_kernel(const int* __restrict__ src, const int* __restrict__ dst,
                           int* __restrict__ deg) {
    int i = blockIdx.x * blockDim.x + threadIdx.x;
    if (i < NE2) {
        int n = (i < NE) ? dst[i] : src[i - NE];
        atomicAdd(&deg[n], 1);
    }
}

__global__ void prefix_kernel(const int* __restrict__ deg, int* __restrict__ row_start,
                              int* __restrict__ cursor) {
    __shared__ int sums[1024];
    int t = threadIdx.x;
    const int CH = (NN + 1023) / 1024;
    int lo = t * CH, hi = lo + CH;
    if (hi > NN) hi = NN;
    if (lo > NN) lo = NN;
    int s = 0;
    for (int n = lo; n < hi; n++) s += deg[n];
    sums[t] = s;
    __syncthreads();
    for (int off = 1; off < 1024; off <<= 1) {
        int v = (t >= off) ? sums[t - off] : 0;
        __syncthreads();
        sums[t] += v;
        __syncthreads();
    }
    int run = (t == 0) ? 0 : sums[t - 1];
    for (int n = lo; n < hi; n++) {
        row_start[n] = run;
        cursor[n] = run;
        run += deg[n];
    }
    if (t == 1023) row_start[NN] = sums[1023];
}

__global__ void scatter_kernel(const int* __restrict__ src, const int* __restrict__ dst,
                               int* __restrict__ cursor, int* __restrict__ elist) {
    int i = blockIdx.x * blockDim.x + threadIdx.x;
    if (i < NE2) {
        int n = (i < NE) ? dst[i] : src[i - NE];
        int pos = atomicAdd(&cursor[n], 1);
        elist[pos] = i;
    }
}

// ---------------------------------------------------------------------------
// fp32 -> bf16 bulk convert, two arrays in one launch
// ---------------------------------------------------------------------------
__global__ void conv2_kernel(const float* __restrict__ a, ushort_t* __restrict__ oa, int na8,
                             const float* __restrict__ b, ushort_t* __restrict__ ob, int nb8) {
    int i = blockIdx.x * 256 + threadIdx.x;
    const float* p;
    ushort_t* o;
    if (i < na8) { p = a + (size_t)i * 8; o = oa + (size_t)i * 8; }
    else {
        int j = i - na8;
        if (j >= nb8) return;
        p = b + (size_t)j * 8; o = ob + (size_t)j * 8;
    }
    float4 u = *(const float4*)p;
    float4 v = *(const float4*)(p + 4);
    union { ushort_t s[8]; uint4 w; } r;
    r.s[0] = f2bf(u.x); r.s[1] = f2bf(u.y); r.s[2] = f2bf(u.z); r.s[3] = f2bf(u.w);
    r.s[4] = f2bf(v.x); r.s[5] = f2bf(v.y); r.s[6] = f2bf(v.z); r.s[7] = f2bf(v.w);
    *(uint4*)o = r.w;
}

// ---------------------------------------------------------------------------
// All weight transposes in one launch. dst[n*stride + koff + k] = bf16(src[k*256+n])
// ---------------------------------------------------------------------------
struct TD { const float* src; ushort_t* dst; int stride, koff, kr; };
struct TA { TD d[8]; };

__global__ void transpose_all_kernel(TA ta) {
    TD t = ta.d[blockIdx.y];
    int k = blockIdx.x;
    if (k >= t.kr) return;
    int n = threadIdx.x;
    t.dst[(size_t)n * t.stride + t.koff + k] = f2bf(t.src[(size_t)k * 256 + n]);
}

// ---------------------------------------------------------------------------
// m97-shape bf16 MFMA GEMM: C[M x 256] = A[M x KTOT] @ B[KTOT x 256]
//  Tile 128 rows x 128 cols, col-half via XCD-pair swizzled blockIdx.
//  4 waves 2x2, acc[4][4] = 64 AGPR, single LDS buffer, 2-barrier K-loop,
//  3 blocks/CU.
//  A seg0 (k<256): bf16 (A0F32=false) or fp32 (A0F32=true, reg-staged+cvt).
//  A seg1 (k>=256, KTOT==512): bf16 at A1/rsA1.
//  Bt/out selected by blockIdx.y (Bt2/out2) for paired launches.
//  EPI: 0 fp32 store, 2 bf16+bias, 3 bf16+bias+relu,
//       4 pred-head PARTIAL (col-half sums; finalize adds + b2 + noise)
// ---------------------------------------------------------------------------
template <int KTOT, int EPI, bool A0F32>
__global__ __launch_bounds__(256, 3) void mfma_gemm(
        const void* __restrict__ A0v, int rsA0,
        const ushort_t* __restrict__ A1, int rsA1,
        const ushort_t* __restrict__ Bt, const ushort_t* __restrict__ Bt2,
        const float* __restrict__ bias,
        void* __restrict__ out, void* __restrict__ out2, int rsOut, int M,
        const int* __restrict__ srcp, const int* __restrict__ dstp,
        const float* __restrict__ Hs, const float* __restrict__ Hd,
        const float* __restrict__ w2) {
    __shared__ ushort_t As[128 * 32];   // 8 KB
    __shared__ ushort_t Bs[128 * 32];   // 8 KB
    __shared__ float red[128];

    int tid = threadIdx.x;
    int lane = tid & 63;
    int wave = tid >> 6;
    int wr = wave >> 1;
    int wc = wave & 1;
    int quad = lane >> 4;
    int col_l = lane & 15;
    int p, colblk;
    pc_map(blockIdx.x, gridDim.x, p, colblk);

    const ushort_t* Bsel = blockIdx.y ? Bt2 : Bt;
    void* Osel = blockIdx.y ? out2 : out;

    f32x4 acc[4][4];
#pragma unroll
    for (int mt = 0; mt < 4; mt++)
#pragma unroll
        for (int nt = 0; nt < 4; nt++) acc[mt][nt] = (f32x4)0.f;

    for (int k0 = 0; k0 < KTOT; k0 += 32) {
        __syncthreads();   // prior reads of As/Bs complete before overwrite
        // B first: async loads fly while the fp32-A path waits on its loads
#pragma unroll
        for (int j = 0; j < 2; j++) {
            int flat = tid + 256 * j;
            int n = flat >> 2, ch = flat & 3;
            const ushort_t* gp = Bsel + (size_t)(colblk * 128 + n) * KTOT + k0 + ch * 8;
            async_cp16(gp, Bs + ((wave * 64 + 256 * j) * 8));
        }
        bool seg1 = (KTOT == 512) && (k0 >= 256);
        if (A0F32 && !seg1) {
            // fp32 A: load 32B/thread, convert, ds_write 16B (same LDS layout)
#pragma unroll
            for (int j = 0; j < 2; j++) {
                int flat = tid + 256 * j;
                int row = flat >> 2, ch = flat & 3;
                int grow = p * 128 + row;
                if (grow >= M) grow = M - 1;
                const float* gp = (const float*)A0v + (size_t)grow * rsA0 + k0 + ch * 8;
                float4 u = *(const float4*)gp;
                float4 v = *(const float4*)(gp + 4);
                union { ushort_t s[8]; uint4 w; } r;
                r.s[0] = f2bf(u.x); r.s[1] = f2bf(u.y); r.s[2] = f2bf(u.z); r.s[3] = f2bf(u.w);
                r.s[4] = f2bf(v.x); r.s[5] = f2bf(v.y); r.s[6] = f2bf(v.z); r.s[7] = f2bf(v.w);
                *(uint4*)(As + (size_t)flat * 8) = r.w;
            }
        } else {
            const ushort_t* abase;
            int rs, koffs;
            if (KTOT == 512 && k0 >= 256) { abase = A1; rs = rsA1; koffs = k0 - 256; }
            else { abase = (const ushort_t*)A0v; rs = rsA0; koffs = k0; }
#pragma unroll
            for (int j = 0; j < 2; j++) {
                int flat = tid + 256 * j;
                int row = flat >> 2, ch = flat & 3;
                int grow = p * 128 + row;
                if (grow >= M) grow = M - 1;
                const ushort_t* gp = abase + (size_t)grow * rs + koffs + ch * 8;
                async_cp16(gp, As + ((wave * 64 + 256 * j) * 8));
            }
        }
        __syncthreads();   // drain: loads landed in LDS

        bf16x8 a[4], b[4];
#pragma unroll
        for (int mt = 0; mt < 4; mt++)
            a[mt] = *(const bf16x8*)(As + (wr * 64 + mt * 16 + col_l) * 32 + quad * 8);
#pragma unroll
        for (int nt = 0; nt < 4; nt++)
            b[nt] = *(const bf16x8*)(Bs + (wc * 64 + nt * 16 + col_l) * 32 + quad * 8);
#pragma unroll
        for (int mt = 0; mt < 4; mt++)
#pragma unroll
            for (int nt = 0; nt < 4; nt++)
                acc[mt][nt] = __builtin_amdgcn_mfma_f32_16x16x32_bf16(
                    a[mt], b[nt], acc[mt][nt], 0, 0, 0);
    }

    if (EPI == 4) {
        // pred-head partial epilogue (this column half only)
        __syncthreads();
        if (tid < 128) red[tid] = 0.f;
        __syncthreads();
        float b1c[4], w2c[4];
#pragma unroll
        for (int nt = 0; nt < 4; nt++) {
            int col = colblk * 128 + wc * 64 + nt * 16 + col_l;
            b1c[nt] = bias[col];
            w2c[nt] = w2[col];
        }
#pragma unroll
        for (int mt = 0; mt < 4; mt++) {
#pragma unroll
            for (int r = 0; r < 4; r++) {
                int lrow = wr * 64 + mt * 16 + quad * 4 + r;
                int e = p * 128 + lrow;
                int ec = e < M ? e : M - 1;
                int s = srcp[ec], d = dstp[ec];
                const float* hsr = Hs + (size_t)s * 256;
                const float* hdr = Hd + (size_t)d * 256;
                float part = 0.f;
#pragma unroll
                for (int nt = 0; nt < 4; nt++) {
                    int col = colblk * 128 + wc * 64 + nt * 16 + col_l;
                    part += fmaxf(acc[mt][nt][r] + hsr[col] + hdr[col] + b1c[nt], 0.f)
                            * w2c[nt];
                }
#pragma unroll
                for (int m = 8; m > 0; m >>= 1) part += __shfl_xor(part, m, 64);
                if (col_l == 0) atomicAdd(&red[lrow], part);
            }
        }
        __syncthreads();
        if (tid < 128) {
            int e = p * 128 + tid;
            if (e < M) {
                float* tgt = colblk ? (float*)out2 : (float*)out;
                tgt[e] = red[tid];
            }
        }
        return;
    }

    float bs[4];
    if (EPI >= 2) {
#pragma unroll
        for (int nt = 0; nt < 4; nt++)
            bs[nt] = bias[colblk * 128 + wc * 64 + nt * 16 + col_l];
    }
#pragma unroll
    for (int mt = 0; mt < 4; mt++) {
#pragma unroll
        for (int nt = 0; nt < 4; nt++) {
            int colg = colblk * 128 + wc * 64 + nt * 16 + col_l;
#pragma unroll
            for (int r = 0; r < 4; r++) {
                int rg = p * 128 + wr * 64 + mt * 16 + quad * 4 + r;
                if (rg < M) {
                    float v = acc[mt][nt][r];
                    if (EPI >= 2) v += bs[nt];
                    if (EPI == 3) v = fmaxf(v, 0.f);
                    if (EPI == 0)
                        ((float*)Osel)[(size_t)rg * rsOut + colg] = v;
                    else
                        ((ushort_t*)Osel)[(size_t)rg * rsOut + colg] = f2bf(v);
                }
            }
        }
    }
}

// ---------------------------------------------------------------------------
// Finalize pred head: logit = part0 + part1 + b2; sampled = sigmoid(logit+noise)
// ---------------------------------------------------------------------------
__global__ void finalize_kernel(float* __restrict__ out, const float* __restrict__ part1,
                                const float* __restrict__ b2v, float* __restrict__ out_s) {
    int e = blockIdx.x * blockDim.x + threadIdx.x;
    if (e >= NE) return;
    float logit = out[e] + part1[e] + b2v[0];
    out[e] = logit;
    unsigned y0, y1;
    threefry2x32(0u, 42u, 0u, (unsigned)e, y0, y1);
    unsigned bits = y0 ^ y1;
    float f = __uint_as_float((bits >> 9) | 0x3F800000u) - 1.0f;
    float u = fmaxf(1e-10f, f + 1e-10f);
    float noise = logf(u) - logf(1.0f - u);
    out_s[e] = 1.0f / (1.0f + expf(-(logit + noise)));
}

// ---------------------------------------------------------------------------
// Edge-attribute sum per node (shared across both SAGE layers):
//  agg_ea[n][c] = sum over incident edges of ea_f (fwd: ea, rev: ea_rev), fp32.
//  One wave per node; lane owns 4 cols.
// ---------------------------------------------------------------------------
__global__ __launch_bounds__(64) void agg_ea_kernel(
        const ushort_t* __restrict__ eaf, const ushort_t* __restrict__ ear,
        const int* __restrict__ row_start, const int* __restrict__ elist,
        float* __restrict__ agg_ea) {
    int n = blockIdx.x;
    int c = threadIdx.x * 4;
    float ax = 0.f, ay = 0.f, az = 0.f, aw = 0.f;
    int beg = row_start[n], end = row_start[n + 1];
    for (int p = beg; p < end; p++) {
        int i = elist[p];
        const ushort_t* er = (i < NE) ? eaf + (size_t)i * 256
                                      : ear + (size_t)(i - NE) * 256;
        ushort4 ev = *(const ushort4*)(er + c);
        ax += bf2f(ev.x); ay += bf2f(ev.y); az += bf2f(ev.z); aw += bf2f(ev.w);
    }
    float4 o; o.x = ax; o.y = ay; o.z = az; o.w = aw;
    *(float4*)(agg_ea + (size_t)n * 256 + c) = o;
}

// ---------------------------------------------------------------------------
// Node-feature mean aggregation: agg[n] = (sum x[srcnode] + agg_ea[n]) / deg.
//  x table is small (10-20 MB -> L2/L3 resident); one gather load per edge.
// ---------------------------------------------------------------------------
__global__ __launch_bounds__(64) void agg_x_kernel(
        const ushort_t* __restrict__ xin, int rsx,
        const int* __restrict__ src, const int* __restrict__ dst,
        const int* __restrict__ row_start, const int* __restrict__ elist,
        const int* __restrict__ deg, const float* __restrict__ agg_ea,
        ushort_t* __restrict__ agg) {
    int n = blockIdx.x;
    int c = threadIdx.x * 4;
    float ax = 0.f, ay = 0.f, az = 0.f, aw = 0.f;
    int beg = row_start[n], end = row_start[n + 1];
    for (int p = beg; p < end; p++) {
        int i = elist[p];
        int node = (i < NE) ? src[i] : dst[i - NE];
        ushort4 xv = *(const ushort4*)(xin + (size_t)node * rsx + c);
        ax += bf2f(xv.x); ay += bf2f(xv.y); az += bf2f(xv.z); aw += bf2f(xv.w);
    }
    float4 e = *(const float4*)(agg_ea + (size_t)n * 256 + c);
    float d = fmaxf((float)deg[n], 1.0f);
    ushort4 o;
    o.x = f2bf((ax + e.x) / d); o.y = f2bf((ay + e.y) / d);
    o.z = f2bf((az + e.z) / d); o.w = f2bf((aw + e.w) / d);
    *(ushort4*)(agg + (size_t)n * 256 + c) = o;
}

// ---------------------------------------------------------------------------
extern "C" void kernel_launch(void* const* d_in, const int* in_sizes, int n_in,
                              void* d_out, int out_size, void* d_ws, size_t ws_size,
                              hipStream_t stream) {
    const float* x        = (const float*)d_in[0];
    const float* ea       = (const float*)d_in[1];
    const float* qemb     = (const float*)d_in[2];
    const int*   eidx     = (const int*)d_in[3];
    const float* W_rev1   = (const float*)d_in[4];
    const float* b_rev1   = (const float*)d_in[5];
    const float* W_rev2   = (const float*)d_in[6];
    const float* b_rev2   = (const float*)d_in[7];
    const float* W_sage1  = (const float*)d_in[8];
    const float* b_sage1  = (const float*)d_in[9];
    const float* W_sage2  = (const float*)d_in[10];
    const float* b_sage2  = (const float*)d_in[11];
    const float* W_pred1  = (const float*)d_in[12];
    const float* b_pred1  = (const float*)d_in[13];
    const float* W_pred2  = (const float*)d_in[14];
    const float* b_pred2  = (const float*)d_in[15];
    float* out = (float*)d_out;

    const int* src = eidx;
    const int* dst = eidx + NE;

    // ---- workspace layout ----
    char* w = (char*)d_ws;
    ushort_t* ea_bf  = (ushort_t*)w; w += (size_t)NE * 256 * 2;   // 102.4 MB
    ushort_t* hid_bf = (ushort_t*)w; w += (size_t)NE * 256 * 2;   // 102.4 MB (rev tmp)
    ushort_t* ea_rev_bf = (ushort_t*)w; w += (size_t)NE * 256 * 2;// 102.4 MB
    ushort_t* x_bf   = (ushort_t*)w; w += (size_t)NN * 256 * 2;
    ushort_t* H      = (ushort_t*)w; w += (size_t)NN * 512 * 2;   // [h1|h2]
    ushort_t* agg_bf = (ushort_t*)w; w += (size_t)NN * 256 * 2;
    float*    Hsrc   = (float*)w;    w += (size_t)NN * 256 * 4;   // also agg_ea (disjoint lifetime)
    float*    Hdst   = (float*)w;    w += (size_t)NN * 256 * 4;
    float*    part1  = (float*)w;    w += (size_t)NE * 4;         // pred col-half 1 partial
    ushort_t* Wt_rev1  = (ushort_t*)w; w += 256 * 256 * 2;
    ushort_t* Wt_rev2  = (ushort_t*)w; w += 256 * 256 * 2;
    ushort_t* Wt_sage1 = (ushort_t*)w; w += 256 * 512 * 2;
    ushort_t* Wt_sage2 = (ushort_t*)w; w += 256 * 512 * 2;
    ushort_t* Wt_src   = (ushort_t*)w; w += 256 * 512 * 2;
    ushort_t* Wt_dst   = (ushort_t*)w; w += 256 * 512 * 2;
    ushort_t* Wt_edge  = (ushort_t*)w; w += 256 * 512 * 2;
    int* deg       = (int*)w; w += (size_t)NN * 4;
    int* row_start = (int*)w; w += (size_t)(NN + 1) * 4;
    int* cursor    = (int*)w; w += (size_t)NN * 4;
    int* elist     = (int*)w; w += (size_t)NE2 * 4;

    float* agg_ea = Hsrc;   // alias: agg_ea dead before Hsrc is written (pair GEMM)

    const int EB = (NE + 127) / 128;   // 1563 row-blocks
    const int NB = (NN + 127) / 128;   // 157 row-blocks

    // ---- CSR ----
    hipMemsetAsync(deg, 0, (size_t)NN * 4, stream);
    deg_kernel<<<(NE2 + 255) / 256, 256, 0, stream>>>(src, dst, deg);
    prefix_kernel<<<1, 1024, 0, stream>>>(deg, row_start, cursor);
    scatter_kernel<<<(NE2 + 255) / 256, 256, 0, stream>>>(src, dst, cursor, elist);

    // ---- all weight transposes, one launch ----
    TA ta;
    ta.d[0] = { W_rev1,  Wt_rev1,  256, 0,   256 };
    ta.d[1] = { W_rev2,  Wt_rev2,  256, 0,   256 };
    ta.d[2] = { W_sage1, Wt_sage1, 512, 0,   512 };
    ta.d[3] = { W_sage2, Wt_sage2, 512, 0,   512 };
    ta.d[4] = { W_pred1 + (size_t)256 * 256,  Wt_src,  512, 0,   512 };
    ta.d[5] = { W_pred1 + (size_t)1024 * 256, Wt_dst,  512, 0,   512 };
    ta.d[6] = { W_pred1,                      Wt_edge, 512, 0,   256 };
    ta.d[7] = { W_pred1 + (size_t)768 * 256,  Wt_edge, 512, 256, 256 };
    transpose_all_kernel<<<dim3(512, 8), 256, 0, stream>>>(ta);

    // ---- activations to bf16 (ea + x, one launch) ----
    conv2_kernel<<<((NE + NN) * 32 + 255) / 256, 256, 0, stream>>>(
        ea, ea_bf, NE * 32, x, x_bf, NN * 32);

    // ---- reverse-edge MLP (two m97-shape GEMMs, col-split + swizzle) ----
    mfma_gemm<256, 3, false><<<EB * 2, 256, 0, stream>>>(
        ea_bf, 256, nullptr, 0, Wt_rev1, nullptr, b_rev1,
        hid_bf, nullptr, 256, NE, nullptr, nullptr, nullptr, nullptr, nullptr);
    mfma_gemm<256, 2, false><<<EB * 2, 256, 0, stream>>>(
        hid_bf, 256, nullptr, 0, Wt_rev2, nullptr, b_rev2,
        ea_rev_bf, nullptr, 256, NE, nullptr, nullptr, nullptr, nullptr, nullptr);

    // ---- shared edge-attr aggregation (once for both SAGE layers) ----
    agg_ea_kernel<<<NN, 64, 0, stream>>>(ea_bf, ea_rev_bf, row_start, elist, agg_ea);

    // ---- SAGE layer 1 ----
    agg_x_kernel<<<NN, 64, 0, stream>>>(x_bf, 256, src, dst, row_start, elist,
                                        deg, agg_ea, agg_bf);
    mfma_gemm<512, 3, false><<<NB * 2, 256, 0, stream>>>(
        x_bf, 256, agg_bf, 256, Wt_sage1, nullptr, b_sage1,
        H, nullptr, 512, NN, nullptr, nullptr, nullptr, nullptr, nullptr);

    // ---- SAGE layer 2 ----
    agg_x_kernel<<<NN, 64, 0, stream>>>(H, 512, src, dst, row_start, elist,
                                        deg, agg_ea, agg_bf);
    mfma_gemm<512, 3, false><<<NB * 2, 256, 0, stream>>>(
        H, 512, agg_bf, 256, Wt_sage2, nullptr, b_sage2,
        H + 256, nullptr, 512, NN, nullptr, nullptr, nullptr, nullptr, nullptr);

    // ---- node-side pred contributions: Hsrc & Hdst in one paired launch ----
    // (writes Hsrc -> agg_ea lifetime ends here)
    mfma_gemm<512, 0, false><<<dim3(NB * 2, 2), 256, 0, stream>>>(
        H, 512, H + 256, 512, Wt_src, Wt_dst, nullptr,
        Hsrc, Hdst, 256, NN, nullptr, nullptr, nullptr, nullptr, nullptr);

    // ---- edge GEMM + fused pred head partials (q read fp32, cvt in staging) ----
    mfma_gemm<512, 4, true><<<EB * 2, 256, 0, stream>>>(
        qemb, 256, ea_bf, 256, Wt_edge, nullptr, b_pred1,
        out, part1, 0, NE, src, dst, Hsrc, Hdst, W_pred2);

    // ---- finalize: add halves + b2, threefry noise, sigmoid ----
    finalize_kernel<<<(NE + 255) / 256, 256, 0, stream>>>(out, part1, b_pred2, out + NE);
}

// Round 6
// 978.524 us; speedup vs baseline: 1.1079x; 1.0047x over previous
//
#include <hip/hip_runtime.h>
#include <cstdint>
#include <cstddef>

#define EMB 256
#define NN 20000
#define NE 200000
#define NE2 400000

typedef unsigned short ushort_t;
typedef __attribute__((ext_vector_type(8))) short bf16x8;
typedef __attribute__((ext_vector_type(4))) float f32x4;

// ---------------------------------------------------------------------------
// bf16 helpers (RNE)
// ---------------------------------------------------------------------------
__device__ __forceinline__ ushort_t f2bf(float f) {
    unsigned u = __float_as_uint(f);
    u += 0x7FFFu + ((u >> 16) & 1u);
    return (ushort_t)(u >> 16);
}
__device__ __forceinline__ float bf2f(ushort_t u) {
    return __uint_as_float(((unsigned)u) << 16);
}

// async global->LDS, 16B per lane. LDS dest = wave-uniform base + lane*16.
__device__ __forceinline__ void async_cp16(const ushort_t* g, ushort_t* l) {
    __builtin_amdgcn_global_load_lds(
        (const __attribute__((address_space(1))) unsigned int*)g,
        (__attribute__((address_space(3))) unsigned int*)l,
        16, 0, 0);
}

// ---------------------------------------------------------------------------
// XCD-pair swizzle for col-split GEMMs: dispatch round-robins blocks over 8
// XCDs; map flat bid so the two col-halves of a row-block are 8 slots apart
// (same XCD, temporally adjacent) -> 2nd A-tile read hits that XCD's L2.
// Verified round 5: pred FETCH dropped to byte-minimal.
// ---------------------------------------------------------------------------
__device__ __forceinline__ void pc_map(int bid, int T, int& p, int& colblk) {
    int Tf = T & ~15;
    if (bid < Tf) {
        p = (bid >> 4) * 8 + (bid & 7);
        colblk = (bid >> 3) & 1;
    } else {
        int rem = bid - Tf;
        int nr = (T - Tf) >> 1;
        p = (T >> 1) - nr + rem % nr;
        colblk = rem / nr;
    }
}

// ---------------------------------------------------------------------------
// Threefry2x32, partitionable mode: bits(e) = o0^o1 of threefry((0,42),(0,e))
// ---------------------------------------------------------------------------
__device__ __forceinline__ unsigned rotl32(unsigned v, int d) {
    return (v << d) | (v >> (32 - d));
}
__device__ __forceinline__ void threefry2x32(unsigned k0, unsigned k1,
                                             unsigned x0, unsigned x1,
                                             unsigned& o0, unsigned& o1) {
    unsigned k2 = k0 ^ k1 ^ 0x1BD11BDAu;
    x0 += k0; x1 += k1;
#define TF_R(r) { x0 += x1; x1 = rotl32(x1, (r)); x1 ^= x0; }
    TF_R(13) TF_R(15) TF_R(26) TF_R(6)
    x0 += k1; x1 += k2 + 1u;
    TF_R(17) TF_R(29) TF_R(16) TF_R(24)
    x0 += k2; x1 += k0 + 2u;
    TF_R(13) TF_R(15) TF_R(26) TF_R(6)
    x0 += k0; x1 += k1 + 3u;
    TF_R(17) TF_R(29) TF_R(16) TF_R(24)
    x0 += k1; x1 += k2 + 4u;
    TF_R(13) TF_R(15) TF_R(26) TF_R(6)
    x0 += k2; x1 += k0 + 5u;
#undef TF_R
    o0 = x0; o1 = x1;
}

// ---------------------------------------------------------------------------
// CSR build
// ---------------------------------------------------------------------------
__global__ void deg_kernel(const int* __restrict__ src, const int* __restrict__ dst,
                           int* __restrict__ deg) {
    int i = blockIdx.x * blockDim.x + threadIdx.x;
    if (i < NE2) {
        int n = (i < NE) ? dst[i] : src[i - NE];
        atomicAdd(&deg[n], 1);
    }
}

__global__ void prefix_kernel(const int* __restrict__ deg, int* __restrict__ row_start,
                              int* __restrict__ cursor) {
    __shared__ int sums[1024];
    int t = threadIdx.x;
    const int CH = (NN + 1023) / 1024;
    int lo = t * CH, hi = lo + CH;
    if (hi > NN) hi = NN;
    if (lo > NN) lo = NN;
    int s = 0;
    for (int n = lo; n < hi; n++) s += deg[n];
    sums[t] = s;
    __syncthreads();
    for (int off = 1; off < 1024; off <<= 1) {
        int v = (t >= off) ? sums[t - off] : 0;
        __syncthreads();
        sums[t] += v;
        __syncthreads();
    }
    int run = (t == 0) ? 0 : sums[t - 1];
    for (int n = lo; n < hi; n++) {
        row_start[n] = run;
        cursor[n] = run;
        run += deg[n];
    }
    if (t == 1023) row_start[NN] = sums[1023];
}

__global__ void scatter_kernel(const int* __restrict__ src, const int* __restrict__ dst,
                               int* __restrict__ cursor, int* __restrict__ elist) {
    int i = blockIdx.x * blockDim.x + threadIdx.x;
    if (i < NE2) {
        int n = (i < NE) ? dst[i] : src[i - NE];
        int pos = atomicAdd(&cursor[n], 1);
        elist[pos] = i;
    }
}

// ---------------------------------------------------------------------------
// fp32 -> bf16 bulk convert, two arrays in one launch
// ---------------------------------------------------------------------------
__global__ void conv2_kernel(const float* __restrict__ a, ushort_t* __restrict__ oa, int na8,
                             const float* __restrict__ b, ushort_t* __restrict__ ob, int nb8) {
    int i = blockIdx.x * 256 + threadIdx.x;
    const float* p;
    ushort_t* o;
    if (i < na8) { p = a + (size_t)i * 8; o = oa + (size_t)i * 8; }
    else {
        int j = i - na8;
        if (j >= nb8) return;
        p = b + (size_t)j * 8; o = ob + (size_t)j * 8;
    }
    float4 u = *(const float4*)p;
    float4 v = *(const float4*)(p + 4);
    union { ushort_t s[8]; uint4 w; } r;
    r.s[0] = f2bf(u.x); r.s[1] = f2bf(u.y); r.s[2] = f2bf(u.z); r.s[3] = f2bf(u.w);
    r.s[4] = f2bf(v.x); r.s[5] = f2bf(v.y); r.s[6] = f2bf(v.z); r.s[7] = f2bf(v.w);
    *(uint4*)o = r.w;
}

// ---------------------------------------------------------------------------
// All weight transposes in one launch. dst[n*stride + koff + k] = bf16(src[k*256+n])
// ---------------------------------------------------------------------------
struct TD { const float* src; ushort_t* dst; int stride, koff, kr; };
struct TA { TD d[8]; };

__global__ void transpose_all_kernel(TA ta) {
    TD t = ta.d[blockIdx.y];
    int k = blockIdx.x;
    if (k >= t.kr) return;
    int n = threadIdx.x;
    t.dst[(size_t)n * t.stride + t.koff + k] = f2bf(t.src[(size_t)k * 256 + n]);
}

// ---------------------------------------------------------------------------
// m97-shape bf16 MFMA GEMM: C[M x 256] = A[M x KTOT] @ B[KTOT x 256]
//  Tile 128 rows x 128 cols, col-half via XCD-pair swizzled blockIdx.
//  4 waves 2x2, acc[4][4] = 64 AGPR.
//  BK=64 as TWO 32-wide sub-buffers (keeps the linear 64B-row layout that
//  global_load_lds requires) -> ONE barrier-drain per 64 K, 32 MFMA per drain.
//  LDS 33 KB, <=128 regs, launch_bounds(256,4) -> 4 blocks/CU target.
//  A seg0 (k<256): bf16 (A0F32=false) or fp32 (A0F32=true, reg-staged+cvt).
//  A seg1 (k>=256, KTOT==512): bf16 at A1/rsA1.
//  Bt/out selected by blockIdx.y (Bt2/out2) for paired launches.
//  EPI: 0 fp32 store, 2 bf16+bias, 3 bf16+bias+relu,
//       4 pred-head PARTIAL (col-half sums; finalize adds + b2 + noise)
// ---------------------------------------------------------------------------
template <int KTOT, int EPI, bool A0F32>
__global__ __launch_bounds__(256, 4) void mfma_gemm(
        const void* __restrict__ A0v, int rsA0,
        const ushort_t* __restrict__ A1, int rsA1,
        const ushort_t* __restrict__ Bt, const ushort_t* __restrict__ Bt2,
        const float* __restrict__ bias,
        void* __restrict__ out, void* __restrict__ out2, int rsOut, int M,
        const int* __restrict__ srcp, const int* __restrict__ dstp,
        const float* __restrict__ Hs, const float* __restrict__ Hd,
        const float* __restrict__ w2) {
    __shared__ ushort_t As[2][128 * 32];   // 2 x 8 KB sub-buffers (k-halves)
    __shared__ ushort_t Bs[2][128 * 32];   // 2 x 8 KB
    __shared__ float red[128];

    int tid = threadIdx.x;
    int lane = tid & 63;
    int wave = tid >> 6;
    int wr = wave >> 1;
    int wc = wave & 1;
    int quad = lane >> 4;
    int col_l = lane & 15;
    int p, colblk;
    pc_map(blockIdx.x, gridDim.x, p, colblk);

    const ushort_t* Bsel = blockIdx.y ? Bt2 : Bt;
    void* Osel = blockIdx.y ? out2 : out;

    f32x4 acc[4][4];
#pragma unroll
    for (int mt = 0; mt < 4; mt++)
#pragma unroll
        for (int nt = 0; nt < 4; nt++) acc[mt][nt] = (f32x4)0.f;

    for (int k0 = 0; k0 < KTOT; k0 += 64) {
        __syncthreads();   // prior reads of As/Bs complete before overwrite
#pragma unroll
        for (int h = 0; h < 2; h++) {
            int kk = k0 + 32 * h;
            // B sub-tile first: async loads fly while fp32-A path waits on its loads
#pragma unroll
            for (int j = 0; j < 2; j++) {
                int flat = tid + 256 * j;
                int n = flat >> 2, ch = flat & 3;
                const ushort_t* gp = Bsel + (size_t)(colblk * 128 + n) * KTOT + kk + ch * 8;
                async_cp16(gp, Bs[h] + ((wave * 64 + 256 * j) * 8));
            }
            bool seg1 = (KTOT == 512) && (kk >= 256);
            if (A0F32 && !seg1) {
                // fp32 A: load 32B/thread, convert, ds_write 16B (same LDS layout)
#pragma unroll
                for (int j = 0; j < 2; j++) {
                    int flat = tid + 256 * j;
                    int row = flat >> 2, ch = flat & 3;
                    int grow = p * 128 + row;
                    if (grow >= M) grow = M - 1;
                    const float* gp = (const float*)A0v + (size_t)grow * rsA0 + kk + ch * 8;
                    float4 u = *(const float4*)gp;
                    float4 v = *(const float4*)(gp + 4);
                    union { ushort_t s[8]; uint4 w; } r;
                    r.s[0] = f2bf(u.x); r.s[1] = f2bf(u.y); r.s[2] = f2bf(u.z); r.s[3] = f2bf(u.w);
                    r.s[4] = f2bf(v.x); r.s[5] = f2bf(v.y); r.s[6] = f2bf(v.z); r.s[7] = f2bf(v.w);
                    *(uint4*)(As[h] + (size_t)flat * 8) = r.w;
                }
            } else {
                const ushort_t* abase;
                int rs, koffs;
                if (KTOT == 512 && kk >= 256) { abase = A1; rs = rsA1; koffs = kk - 256; }
                else { abase = (const ushort_t*)A0v; rs = rsA0; koffs = kk; }
#pragma unroll
                for (int j = 0; j < 2; j++) {
                    int flat = tid + 256 * j;
                    int row = flat >> 2, ch = flat & 3;
                    int grow = p * 128 + row;
                    if (grow >= M) grow = M - 1;
                    const ushort_t* gp = abase + (size_t)grow * rs + koffs + ch * 8;
                    async_cp16(gp, As[h] + ((wave * 64 + 256 * j) * 8));
                }
            }
        }
        __syncthreads();   // single drain per 64-K step

#pragma unroll
        for (int h = 0; h < 2; h++) {
            bf16x8 a[4], b[4];
#pragma unroll
            for (int mt = 0; mt < 4; mt++)
                a[mt] = *(const bf16x8*)(As[h] + (wr * 64 + mt * 16 + col_l) * 32 + quad * 8);
#pragma unroll
            for (int nt = 0; nt < 4; nt++)
                b[nt] = *(const bf16x8*)(Bs[h] + (wc * 64 + nt * 16 + col_l) * 32 + quad * 8);
#pragma unroll
            for (int mt = 0; mt < 4; mt++)
#pragma unroll
                for (int nt = 0; nt < 4; nt++)
                    acc[mt][nt] = __builtin_amdgcn_mfma_f32_16x16x32_bf16(
                        a[mt], b[nt], acc[mt][nt], 0, 0, 0);
        }
    }

    if (EPI == 4) {
        // pred-head partial epilogue (this column half only)
        __syncthreads();
        if (tid < 128) red[tid] = 0.f;
        __syncthreads();
        float b1c[4], w2c[4];
#pragma unroll
        for (int nt = 0; nt < 4; nt++) {
            int col = colblk * 128 + wc * 64 + nt * 16 + col_l;
            b1c[nt] = bias[col];
            w2c[nt] = w2[col];
        }
#pragma unroll
        for (int mt = 0; mt < 4; mt++) {
#pragma unroll
            for (int r = 0; r < 4; r++) {
                int lrow = wr * 64 + mt * 16 + quad * 4 + r;
                int e = p * 128 + lrow;
                int ec = e < M ? e : M - 1;
                int s = srcp[ec], d = dstp[ec];
                const float* hsr = Hs + (size_t)s * 256;
                const float* hdr = Hd + (size_t)d * 256;
                float part = 0.f;
#pragma unroll
                for (int nt = 0; nt < 4; nt++) {
                    int col = colblk * 128 + wc * 64 + nt * 16 + col_l;
                    part += fmaxf(acc[mt][nt][r] + hsr[col] + hdr[col] + b1c[nt], 0.f)
                            * w2c[nt];
                }
#pragma unroll
                for (int m = 8; m > 0; m >>= 1) part += __shfl_xor(part, m, 64);
                if (col_l == 0) atomicAdd(&red[lrow], part);
            }
        }
        __syncthreads();
        if (tid < 128) {
            int e = p * 128 + tid;
            if (e < M) {
                float* tgt = colblk ? (float*)out2 : (float*)out;
                tgt[e] = red[tid];
            }
        }
        return;
    }

    float bs[4];
    if (EPI >= 2) {
#pragma unroll
        for (int nt = 0; nt < 4; nt++)
            bs[nt] = bias[colblk * 128 + wc * 64 + nt * 16 + col_l];
    }
#pragma unroll
    for (int mt = 0; mt < 4; mt++) {
#pragma unroll
        for (int nt = 0; nt < 4; nt++) {
            int colg = colblk * 128 + wc * 64 + nt * 16 + col_l;
#pragma unroll
            for (int r = 0; r < 4; r++) {
                int rg = p * 128 + wr * 64 + mt * 16 + quad * 4 + r;
                if (rg < M) {
                    float v = acc[mt][nt][r];
                    if (EPI >= 2) v += bs[nt];
                    if (EPI == 3) v = fmaxf(v, 0.f);
                    if (EPI == 0)
                        ((float*)Osel)[(size_t)rg * rsOut + colg] = v;
                    else
                        ((ushort_t*)Osel)[(size_t)rg * rsOut + colg] = f2bf(v);
                }
            }
        }
    }
}

// ---------------------------------------------------------------------------
// Finalize pred head: logit = part0 + part1 + b2; sampled = sigmoid(logit+noise)
// ---------------------------------------------------------------------------
__global__ void finalize_kernel(float* __restrict__ out, const float* __restrict__ part1,
                                const float* __restrict__ b2v, float* __restrict__ out_s) {
    int e = blockIdx.x * blockDim.x + threadIdx.x;
    if (e >= NE) return;
    float logit = out[e] + part1[e] + b2v[0];
    out[e] = logit;
    unsigned y0, y1;
    threefry2x32(0u, 42u, 0u, (unsigned)e, y0, y1);
    unsigned bits = y0 ^ y1;
    float f = __uint_as_float((bits >> 9) | 0x3F800000u) - 1.0f;
    float u = fmaxf(1e-10f, f + 1e-10f);
    float noise = logf(u) - logf(1.0f - u);
    out_s[e] = 1.0f / (1.0f + expf(-(logit + noise)));
}

// ---------------------------------------------------------------------------
// Edge-attribute sum per node (shared across both SAGE layers):
//  agg_ea[n][c] = sum over incident edges of ea_f (fwd: ea, rev: ea_rev), fp32.
//  One wave per node; lane owns 4 cols.
// ---------------------------------------------------------------------------
__global__ __launch_bounds__(64) void agg_ea_kernel(
        const ushort_t* __restrict__ eaf, const ushort_t* __restrict__ ear,
        const int* __restrict__ row_start, const int* __restrict__ elist,
        float* __restrict__ agg_ea) {
    int n = blockIdx.x;
    int c = threadIdx.x * 4;
    float ax = 0.f, ay = 0.f, az = 0.f, aw = 0.f;
    int beg = row_start[n], end = row_start[n + 1];
    for (int p = beg; p < end; p++) {
        int i = elist[p];
        const ushort_t* er = (i < NE) ? eaf + (size_t)i * 256
                                      : ear + (size_t)(i - NE) * 256;
        ushort4 ev = *(const ushort4*)(er + c);
        ax += bf2f(ev.x); ay += bf2f(ev.y); az += bf2f(ev.z); aw += bf2f(ev.w);
    }
    float4 o; o.x = ax; o.y = ay; o.z = az; o.w = aw;
    *(float4*)(agg_ea + (size_t)n * 256 + c) = o;
}

// ---------------------------------------------------------------------------
// Node-feature mean aggregation: agg[n] = (sum x[srcnode] + agg_ea[n]) / deg.
//  x table is small (10-20 MB -> L2/L3 resident); one gather load per edge.
// ---------------------------------------------------------------------------
__global__ __launch_bounds__(64) void agg_x_kernel(
        const ushort_t* __restrict__ xin, int rsx,
        const int* __restrict__ src, const int* __restrict__ dst,
        const int* __restrict__ row_start, const int* __restrict__ elist,
        const int* __restrict__ deg, const float* __restrict__ agg_ea,
        ushort_t* __restrict__ agg) {
    int n = blockIdx.x;
    int c = threadIdx.x * 4;
    float ax = 0.f, ay = 0.f, az = 0.f, aw = 0.f;
    int beg = row_start[n], end = row_start[n + 1];
    for (int p = beg; p < end; p++) {
        int i = elist[p];
        int node = (i < NE) ? src[i] : dst[i - NE];
        ushort4 xv = *(const ushort4*)(xin + (size_t)node * rsx + c);
        ax += bf2f(xv.x); ay += bf2f(xv.y); az += bf2f(xv.z); aw += bf2f(xv.w);
    }
    float4 e = *(const float4*)(agg_ea + (size_t)n * 256 + c);
    float d = fmaxf((float)deg[n], 1.0f);
    ushort4 o;
    o.x = f2bf((ax + e.x) / d); o.y = f2bf((ay + e.y) / d);
    o.z = f2bf((az + e.z) / d); o.w = f2bf((aw + e.w) / d);
    *(ushort4*)(agg + (size_t)n * 256 + c) = o;
}

// ---------------------------------------------------------------------------
extern "C" void kernel_launch(void* const* d_in, const int* in_sizes, int n_in,
                              void* d_out, int out_size, void* d_ws, size_t ws_size,
                              hipStream_t stream) {
    const float* x        = (const float*)d_in[0];
    const float* ea       = (const float*)d_in[1];
    const float* qemb     = (const float*)d_in[2];
    const int*   eidx     = (const int*)d_in[3];
    const float* W_rev1   = (const float*)d_in[4];
    const float* b_rev1   = (const float*)d_in[5];
    const float* W_rev2   = (const float*)d_in[6];
    const float* b_rev2   = (const float*)d_in[7];
    const float* W_sage1  = (const float*)d_in[8];
    const float* b_sage1  = (const float*)d_in[9];
    const float* W_sage2  = (const float*)d_in[10];
    const float* b_sage2  = (const float*)d_in[11];
    const float* W_pred1  = (const float*)d_in[12];
    const float* b_pred1  = (const float*)d_in[13];
    const float* W_pred2  = (const float*)d_in[14];
    const float* b_pred2  = (const float*)d_in[15];
    float* out = (float*)d_out;

    const int* src = eidx;
    const int* dst = eidx + NE;

    // ---- workspace layout ----
    char* w = (char*)d_ws;
    ushort_t* ea_bf  = (ushort_t*)w; w += (size_t)NE * 256 * 2;   // 102.4 MB
    ushort_t* hid_bf = (ushort_t*)w; w += (size_t)NE * 256 * 2;   // 102.4 MB (rev tmp)
    ushort_t* ea_rev_bf = (ushort_t*)w; w += (size_t)NE * 256 * 2;// 102.4 MB
    ushort_t* x_bf   = (ushort_t*)w; w += (size_t)NN * 256 * 2;
    ushort_t* H      = (ushort_t*)w; w += (size_t)NN * 512 * 2;   // [h1|h2]
    ushort_t* agg_bf = (ushort_t*)w; w += (size_t)NN * 256 * 2;
    float*    Hsrc   = (float*)w;    w += (size_t)NN * 256 * 4;   // also agg_ea (disjoint lifetime)
    float*    Hdst   = (float*)w;    w += (size_t)NN * 256 * 4;
    float*    part1  = (float*)w;    w += (size_t)NE * 4;         // pred col-half 1 partial
    ushort_t* Wt_rev1  = (ushort_t*)w; w += 256 * 256 * 2;
    ushort_t* Wt_rev2  = (ushort_t*)w; w += 256 * 256 * 2;
    ushort_t* Wt_sage1 = (ushort_t*)w; w += 256 * 512 * 2;
    ushort_t* Wt_sage2 = (ushort_t*)w; w += 256 * 512 * 2;
    ushort_t* Wt_src   = (ushort_t*)w; w += 256 * 512 * 2;
    ushort_t* Wt_dst   = (ushort_t*)w; w += 256 * 512 * 2;
    ushort_t* Wt_edge  = (ushort_t*)w; w += 256 * 512 * 2;
    int* deg       = (int*)w; w += (size_t)NN * 4;
    int* row_start = (int*)w; w += (size_t)(NN + 1) * 4;
    int* cursor    = (int*)w; w += (size_t)NN * 4;
    int* elist     = (int*)w; w += (size_t)NE2 * 4;

    float* agg_ea = Hsrc;   // alias: agg_ea dead before Hsrc is written (pair GEMM)

    const int EB = (NE + 127) / 128;   // 1563 row-blocks
    const int NB = (NN + 127) / 128;   // 157 row-blocks

    // ---- CSR ----
    hipMemsetAsync(deg, 0, (size_t)NN * 4, stream);
    deg_kernel<<<(NE2 + 255) / 256, 256, 0, stream>>>(src, dst, deg);
    prefix_kernel<<<1, 1024, 0, stream>>>(deg, row_start, cursor);
    scatter_kernel<<<(NE2 + 255) / 256, 256, 0, stream>>>(src, dst, cursor, elist);

    // ---- all weight transposes, one launch ----
    TA ta;
    ta.d[0] = { W_rev1,  Wt_rev1,  256, 0,   256 };
    ta.d[1] = { W_rev2,  Wt_rev2,  256, 0,   256 };
    ta.d[2] = { W_sage1, Wt_sage1, 512, 0,   512 };
    ta.d[3] = { W_sage2, Wt_sage2, 512, 0,   512 };
    ta.d[4] = { W_pred1 + (size_t)256 * 256,  Wt_src,  512, 0,   512 };
    ta.d[5] = { W_pred1 + (size_t)1024 * 256, Wt_dst,  512, 0,   512 };
    ta.d[6] = { W_pred1,                      Wt_edge, 512, 0,   256 };
    ta.d[7] = { W_pred1 + (size_t)768 * 256,  Wt_edge, 512, 256, 256 };
    transpose_all_kernel<<<dim3(512, 8), 256, 0, stream>>>(ta);

    // ---- activations to bf16 (ea + x, one launch) ----
    conv2_kernel<<<((NE + NN) * 32 + 255) / 256, 256, 0, stream>>>(
        ea, ea_bf, NE * 32, x, x_bf, NN * 32);

    // ---- reverse-edge MLP (two m97-shape GEMMs, col-split + swizzle) ----
    mfma_gemm<256, 3, false><<<EB * 2, 256, 0, stream>>>(
        ea_bf, 256, nullptr, 0, Wt_rev1, nullptr, b_rev1,
        hid_bf, nullptr, 256, NE, nullptr, nullptr, nullptr, nullptr, nullptr);
    mfma_gemm<256, 2, false><<<EB * 2, 256, 0, stream>>>(
        hid_bf, 256, nullptr, 0, Wt_rev2, nullptr, b_rev2,
        ea_rev_bf, nullptr, 256, NE, nullptr, nullptr, nullptr, nullptr, nullptr);

    // ---- shared edge-attr aggregation (once for both SAGE layers) ----
    agg_ea_kernel<<<NN, 64, 0, stream>>>(ea_bf, ea_rev_bf, row_start, elist, agg_ea);

    // ---- SAGE layer 1 ----
    agg_x_kernel<<<NN, 64, 0, stream>>>(x_bf, 256, src, dst, row_start, elist,
                                        deg, agg_ea, agg_bf);
    mfma_gemm<512, 3, false><<<NB * 2, 256, 0, stream>>>(
        x_bf, 256, agg_bf, 256, Wt_sage1, nullptr, b_sage1,
        H, nullptr, 512, NN, nullptr, nullptr, nullptr, nullptr, nullptr);

    // ---- SAGE layer 2 ----
    agg_x_kernel<<<NN, 64, 0, stream>>>(H, 512, src, dst, row_start, elist,
                                        deg, agg_ea, agg_bf);
    mfma_gemm<512, 3, false><<<NB * 2, 256, 0, stream>>>(
        H, 512, agg_bf, 256, Wt_sage2, nullptr, b_sage2,
        H + 256, nullptr, 512, NN, nullptr, nullptr, nullptr, nullptr, nullptr);

    // ---- node-side pred contributions: Hsrc & Hdst in one paired launch ----
    // (writes Hsrc -> agg_ea lifetime ends here)
    mfma_gemm<512, 0, false><<<dim3(NB * 2, 2), 256, 0, stream>>>(
        H, 512, H + 256, 512, Wt_src, Wt_dst, nullptr,
        Hsrc, Hdst, 256, NN, nullptr, nullptr, nullptr, nullptr, nullptr);

    // ---- edge GEMM + fused pred head partials (q read fp32, cvt in staging) ----
    mfma_gemm<512, 4, true><<<EB * 2, 256, 0, stream>>>(
        qemb, 256, ea_bf, 256, Wt_edge, nullptr, b_pred1,
        out, part1, 0, NE, src, dst, Hsrc, Hdst, W_pred2);

    // ---- finalize: add halves + b2, threefry noise, sigmoid ----
    finalize_kernel<<<(NE + 255) / 256, 256, 0, stream>>>(out, part1, b_pred2, out + NE);
}

// Round 7
// 951.859 us; speedup vs baseline: 1.1389x; 1.0280x over previous
//
#include <hip/hip_runtime.h>
#include <cstdint>
#include <cstddef>

#define EMB 256
#define NN 20000
#define NE 200000
#define NE2 400000

typedef unsigned short ushort_t;
typedef __attribute__((ext_vector_type(8))) short bf16x8;
typedef __attribute__((ext_vector_type(4))) float f32x4;

// ---------------------------------------------------------------------------
// bf16 helpers (RNE)
// ---------------------------------------------------------------------------
__device__ __forceinline__ ushort_t f2bf(float f) {
    unsigned u = __float_as_uint(f);
    u += 0x7FFFu + ((u >> 16) & 1u);
    return (ushort_t)(u >> 16);
}
__device__ __forceinline__ float bf2f(ushort_t u) {
    return __uint_as_float(((unsigned)u) << 16);
}

// async global->LDS, 16B per lane. LDS dest = wave-uniform base + lane*16.
__device__ __forceinline__ void async_cp16(const ushort_t* g, ushort_t* l) {
    __builtin_amdgcn_global_load_lds(
        (const __attribute__((address_space(1))) unsigned int*)g,
        (__attribute__((address_space(3))) unsigned int*)l,
        16, 0, 0);
}

// ---------------------------------------------------------------------------
// XCD-pair swizzle for col-split GEMMs (verified round 5: FETCH byte-minimal)
// ---------------------------------------------------------------------------
__device__ __forceinline__ void pc_map(int bid, int T, int& p, int& colblk) {
    int Tf = T & ~15;
    if (bid < Tf) {
        p = (bid >> 4) * 8 + (bid & 7);
        colblk = (bid >> 3) & 1;
    } else {
        int rem = bid - Tf;
        int nr = (T - Tf) >> 1;
        p = (T >> 1) - nr + rem % nr;
        colblk = rem / nr;
    }
}

// ---------------------------------------------------------------------------
// Threefry2x32, partitionable mode: bits(e) = o0^o1 of threefry((0,42),(0,e))
// ---------------------------------------------------------------------------
__device__ __forceinline__ unsigned rotl32(unsigned v, int d) {
    return (v << d) | (v >> (32 - d));
}
__device__ __forceinline__ void threefry2x32(unsigned k0, unsigned k1,
                                             unsigned x0, unsigned x1,
                                             unsigned& o0, unsigned& o1) {
    unsigned k2 = k0 ^ k1 ^ 0x1BD11BDAu;
    x0 += k0; x1 += k1;
#define TF_R(r) { x0 += x1; x1 = rotl32(x1, (r)); x1 ^= x0; }
    TF_R(13) TF_R(15) TF_R(26) TF_R(6)
    x0 += k1; x1 += k2 + 1u;
    TF_R(17) TF_R(29) TF_R(16) TF_R(24)
    x0 += k2; x1 += k0 + 2u;
    TF_R(13) TF_R(15) TF_R(26) TF_R(6)
    x0 += k0; x1 += k1 + 3u;
    TF_R(17) TF_R(29) TF_R(16) TF_R(24)
    x0 += k1; x1 += k2 + 4u;
    TF_R(13) TF_R(15) TF_R(26) TF_R(6)
    x0 += k2; x1 += k0 + 5u;
#undef TF_R
    o0 = x0; o1 = x1;
}

// ---------------------------------------------------------------------------
// CSR build
// ---------------------------------------------------------------------------
__global__ void deg_kernel(const int* __restrict__ src, const int* __restrict__ dst,
                           int* __restrict__ deg) {
    int i = blockIdx.x * blockDim.x + threadIdx.x;
    if (i < NE2) {
        int n = (i < NE) ? dst[i] : src[i - NE];
        atomicAdd(&deg[n], 1);
    }
}

__global__ void prefix_kernel(const int* __restrict__ deg, int* __restrict__ row_start,
                              int* __restrict__ cursor) {
    __shared__ int sums[1024];
    int t = threadIdx.x;
    const int CH = (NN + 1023) / 1024;
    int lo = t * CH, hi = lo + CH;
    if (hi > NN) hi = NN;
    if (lo > NN) lo = NN;
    int s = 0;
    for (int n = lo; n < hi; n++) s += deg[n];
    sums[t] = s;
    __syncthreads();
    for (int off = 1; off < 1024; off <<= 1) {
        int v = (t >= off) ? sums[t - off] : 0;
        __syncthreads();
        sums[t] += v;
        __syncthreads();
    }
    int run = (t == 0) ? 0 : sums[t - 1];
    for (int n = lo; n < hi; n++) {
        row_start[n] = run;
        cursor[n] = run;
        run += deg[n];
    }
    if (t == 1023) row_start[NN] = sums[1023];
}

__global__ void scatter_kernel(const int* __restrict__ src, const int* __restrict__ dst,
                               int* __restrict__ cursor, int* __restrict__ elist) {
    int i = blockIdx.x * blockDim.x + threadIdx.x;
    if (i < NE2) {
        int n = (i < NE) ? dst[i] : src[i - NE];
        int pos = atomicAdd(&cursor[n], 1);
        elist[pos] = i;
    }
}

// ---------------------------------------------------------------------------
// fp32 -> bf16 bulk convert, two arrays in one launch
// ---------------------------------------------------------------------------
__global__ void conv2_kernel(const float* __restrict__ a, ushort_t* __restrict__ oa, int na8,
                             const float* __restrict__ b, ushort_t* __restrict__ ob, int nb8) {
    int i = blockIdx.x * 256 + threadIdx.x;
    const float* p;
    ushort_t* o;
    if (i < na8) { p = a + (size_t)i * 8; o = oa + (size_t)i * 8; }
    else {
        int j = i - na8;
        if (j >= nb8) return;
        p = b + (size_t)j * 8; o = ob + (size_t)j * 8;
    }
    float4 u = *(const float4*)p;
    float4 v = *(const float4*)(p + 4);
    union { ushort_t s[8]; uint4 w; } r;
    r.s[0] = f2bf(u.x); r.s[1] = f2bf(u.y); r.s[2] = f2bf(u.z); r.s[3] = f2bf(u.w);
    r.s[4] = f2bf(v.x); r.s[5] = f2bf(v.y); r.s[6] = f2bf(v.z); r.s[7] = f2bf(v.w);
    *(uint4*)o = r.w;
}

// ---------------------------------------------------------------------------
// All weight transposes in one launch. dst[n*stride + koff + k] = bf16(src[k*256+n])
// ---------------------------------------------------------------------------
struct TD { const float* src; ushort_t* dst; int stride, koff, kr; };
struct TA { TD d[8]; };

__global__ void transpose_all_kernel(TA ta) {
    TD t = ta.d[blockIdx.y];
    int k = blockIdx.x;
    if (k >= t.kr) return;
    int n = threadIdx.x;
    t.dst[(size_t)n * t.stride + t.koff + k] = f2bf(t.src[(size_t)k * 256 + n]);
}

// ---------------------------------------------------------------------------
// LEAN fused reverse-edge MLP: ea_rev = relu(ea @ W1 + b1) @ W2 + b2
//  64-row tile (3125 blocks, exact). 4 waves 2x2: acc[2][8] = 64 AGPR ONLY.
//  Phase 1 (K=256, HBM A): m97 2-barrier loop -> acc = ea @ W1.
//  h written DIRECTLY from acc to LDS Hl[64][264] (pad keeps 16B row align,
//  2-way bank conflict = free). acc re-zeroed and REUSED for phase 2 (no
//  packed-h registers -> no spill; round-4 failure was spill: WRITE 203MB).
//  Phase 2 (K=256, A from LDS, B = Wt2 L2-resident): 8 short steps.
//  LDS 54.3 KB -> 2-3 blocks/CU. HBM streams: ea in (102MB) + out (102MB).
// ---------------------------------------------------------------------------
__global__ __launch_bounds__(256, 3) void rev_fused_kernel(
        const ushort_t* __restrict__ ea_bf,
        const ushort_t* __restrict__ Wt1, const float* __restrict__ b1,
        const ushort_t* __restrict__ Wt2, const float* __restrict__ b2,
        ushort_t* __restrict__ ea_rev) {
    __shared__ ushort_t As[64 * 32];     // 4 KB
    __shared__ ushort_t Bs[256 * 32];    // 16 KB
    __shared__ ushort_t Hl[64 * 264];    // 33.75 KB (stride 264: 16B-aligned rows)

    int tid = threadIdx.x;
    int lane = tid & 63, wave = tid >> 6;
    int wr = wave >> 1, wc = wave & 1;
    int quad = lane >> 4, col_l = lane & 15;
    int p = blockIdx.x;                  // 64-row tile; 3125*64 == NE exactly

    f32x4 acc[2][8];
#pragma unroll
    for (int mt = 0; mt < 2; mt++)
#pragma unroll
        for (int nt = 0; nt < 8; nt++) acc[mt][nt] = (f32x4)0.f;

    // ---- phase 1: acc = ea @ W1 (K=256) ----
    for (int k0 = 0; k0 < 256; k0 += 32) {
        __syncthreads();
        {   // A tile 64x32 = 4KB: one cp16 per lane
            int row = tid >> 2, ch = tid & 3;
            async_cp16(ea_bf + (size_t)(p * 64 + row) * 256 + k0 + ch * 8,
                       As + (wave * 64) * 8);
        }
#pragma unroll
        for (int j = 0; j < 4; j++) {   // B tile 256x32 = 16KB
            int flat = tid + 256 * j;
            int n = flat >> 2, ch = flat & 3;
            async_cp16(Wt1 + (size_t)n * 256 + k0 + ch * 8,
                       Bs + (wave * 64 + 256 * j) * 8);
        }
        __syncthreads();
        bf16x8 a[2], b[8];
#pragma unroll
        for (int mt = 0; mt < 2; mt++)
            a[mt] = *(const bf16x8*)(As + (wr * 32 + mt * 16 + col_l) * 32 + quad * 8);
#pragma unroll
        for (int nt = 0; nt < 8; nt++)
            b[nt] = *(const bf16x8*)(Bs + (wc * 128 + nt * 16 + col_l) * 32 + quad * 8);
#pragma unroll
        for (int mt = 0; mt < 2; mt++)
#pragma unroll
            for (int nt = 0; nt < 8; nt++)
                acc[mt][nt] = __builtin_amdgcn_mfma_f32_16x16x32_bf16(
                    a[mt], b[nt], acc[mt][nt], 0, 0, 0);
    }

    // ---- h = relu(acc + b1) -> LDS directly; then acc reused for phase 2 ----
    __syncthreads();   // all phase-1 Bs reads done (Hl overlaps nothing, but
                       // keep the write ordered after compute for all waves)
#pragma unroll
    for (int nt = 0; nt < 8; nt++) {
        int lcol = wc * 128 + nt * 16 + col_l;
        float bb = b1[lcol];
#pragma unroll
        for (int mt = 0; mt < 2; mt++)
#pragma unroll
            for (int r = 0; r < 4; r++) {
                int lrow = wr * 32 + mt * 16 + quad * 4 + r;
                Hl[lrow * 264 + lcol] = f2bf(fmaxf(acc[mt][nt][r] + bb, 0.f));
            }
    }
#pragma unroll
    for (int mt = 0; mt < 2; mt++)
#pragma unroll
        for (int nt = 0; nt < 8; nt++) acc[mt][nt] = (f32x4)0.f;

    // ---- phase 2: acc = h @ W2 (K=256, A from LDS, B L2-resident) ----
    for (int k0 = 0; k0 < 256; k0 += 32) {
        __syncthreads();   // prior Bs readers done (step 0: orders Hl writes)
#pragma unroll
        for (int j = 0; j < 4; j++) {
            int flat = tid + 256 * j;
            int n = flat >> 2, ch = flat & 3;
            async_cp16(Wt2 + (size_t)n * 256 + k0 + ch * 8,
                       Bs + (wave * 64 + 256 * j) * 8);
        }
        __syncthreads();
        bf16x8 a[2], b[8];
#pragma unroll
        for (int mt = 0; mt < 2; mt++)
            a[mt] = *(const bf16x8*)(Hl + (wr * 32 + mt * 16 + col_l) * 264
                                     + k0 + quad * 8);
#pragma unroll
        for (int nt = 0; nt < 8; nt++)
            b[nt] = *(const bf16x8*)(Bs + (wc * 128 + nt * 16 + col_l) * 32 + quad * 8);
#pragma unroll
        for (int mt = 0; mt < 2; mt++)
#pragma unroll
            for (int nt = 0; nt < 8; nt++)
                acc[mt][nt] = __builtin_amdgcn_mfma_f32_16x16x32_bf16(
                    a[mt], b[nt], acc[mt][nt], 0, 0, 0);
    }

    // ---- store ea_rev = acc + b2 (bf16) ----
#pragma unroll
    for (int nt = 0; nt < 8; nt++) {
        int colg = wc * 128 + nt * 16 + col_l;
        float bb = b2[colg];
#pragma unroll
        for (int mt = 0; mt < 2; mt++)
#pragma unroll
            for (int r = 0; r < 4; r++) {
                int rg = p * 64 + wr * 32 + mt * 16 + quad * 4 + r;
                ea_rev[(size_t)rg * 256 + colg] = f2bf(acc[mt][nt][r] + bb);
            }
    }
}

// ---------------------------------------------------------------------------
// m97-shape bf16 MFMA GEMM (round-6 template: BK=64 two sub-buffers).
//  EPI: 0 fp32 store, 2 bf16+bias, 3 bf16+bias+relu,
//       4 pred-head PARTIAL (col-half sums; finalize adds + b2 + noise)
// ---------------------------------------------------------------------------
template <int KTOT, int EPI, bool A0F32>
__global__ __launch_bounds__(256, 4) void mfma_gemm(
        const void* __restrict__ A0v, int rsA0,
        const ushort_t* __restrict__ A1, int rsA1,
        const ushort_t* __restrict__ Bt, const ushort_t* __restrict__ Bt2,
        const float* __restrict__ bias,
        void* __restrict__ out, void* __restrict__ out2, int rsOut, int M,
        const int* __restrict__ srcp, const int* __restrict__ dstp,
        const float* __restrict__ Hs, const float* __restrict__ Hd,
        const float* __restrict__ w2) {
    __shared__ ushort_t As[2][128 * 32];
    __shared__ ushort_t Bs[2][128 * 32];
    __shared__ float red[128];

    int tid = threadIdx.x;
    int lane = tid & 63;
    int wave = tid >> 6;
    int wr = wave >> 1;
    int wc = wave & 1;
    int quad = lane >> 4;
    int col_l = lane & 15;
    int p, colblk;
    pc_map(blockIdx.x, gridDim.x, p, colblk);

    const ushort_t* Bsel = blockIdx.y ? Bt2 : Bt;
    void* Osel = blockIdx.y ? out2 : out;

    f32x4 acc[4][4];
#pragma unroll
    for (int mt = 0; mt < 4; mt++)
#pragma unroll
        for (int nt = 0; nt < 4; nt++) acc[mt][nt] = (f32x4)0.f;

    for (int k0 = 0; k0 < KTOT; k0 += 64) {
        __syncthreads();
#pragma unroll
        for (int h = 0; h < 2; h++) {
            int kk = k0 + 32 * h;
#pragma unroll
            for (int j = 0; j < 2; j++) {
                int flat = tid + 256 * j;
                int n = flat >> 2, ch = flat & 3;
                const ushort_t* gp = Bsel + (size_t)(colblk * 128 + n) * KTOT + kk + ch * 8;
                async_cp16(gp, Bs[h] + ((wave * 64 + 256 * j) * 8));
            }
            bool seg1 = (KTOT == 512) && (kk >= 256);
            if (A0F32 && !seg1) {
#pragma unroll
                for (int j = 0; j < 2; j++) {
                    int flat = tid + 256 * j;
                    int row = flat >> 2, ch = flat & 3;
                    int grow = p * 128 + row;
                    if (grow >= M) grow = M - 1;
                    const float* gp = (const float*)A0v + (size_t)grow * rsA0 + kk + ch * 8;
                    float4 u = *(const float4*)gp;
                    float4 v = *(const float4*)(gp + 4);
                    union { ushort_t s[8]; uint4 w; } r;
                    r.s[0] = f2bf(u.x); r.s[1] = f2bf(u.y); r.s[2] = f2bf(u.z); r.s[3] = f2bf(u.w);
                    r.s[4] = f2bf(v.x); r.s[5] = f2bf(v.y); r.s[6] = f2bf(v.z); r.s[7] = f2bf(v.w);
                    *(uint4*)(As[h] + (size_t)flat * 8) = r.w;
                }
            } else {
                const ushort_t* abase;
                int rs, koffs;
                if (KTOT == 512 && kk >= 256) { abase = A1; rs = rsA1; koffs = kk - 256; }
                else { abase = (const ushort_t*)A0v; rs = rsA0; koffs = kk; }
#pragma unroll
                for (int j = 0; j < 2; j++) {
                    int flat = tid + 256 * j;
                    int row = flat >> 2, ch = flat & 3;
                    int grow = p * 128 + row;
                    if (grow >= M) grow = M - 1;
                    const ushort_t* gp = abase + (size_t)grow * rs + koffs + ch * 8;
                    async_cp16(gp, As[h] + ((wave * 64 + 256 * j) * 8));
                }
            }
        }
        __syncthreads();

#pragma unroll
        for (int h = 0; h < 2; h++) {
            bf16x8 a[4], b[4];
#pragma unroll
            for (int mt = 0; mt < 4; mt++)
                a[mt] = *(const bf16x8*)(As[h] + (wr * 64 + mt * 16 + col_l) * 32 + quad * 8);
#pragma unroll
            for (int nt = 0; nt < 4; nt++)
                b[nt] = *(const bf16x8*)(Bs[h] + (wc * 64 + nt * 16 + col_l) * 32 + quad * 8);
#pragma unroll
            for (int mt = 0; mt < 4; mt++)
#pragma unroll
                for (int nt = 0; nt < 4; nt++)
                    acc[mt][nt] = __builtin_amdgcn_mfma_f32_16x16x32_bf16(
                        a[mt], b[nt], acc[mt][nt], 0, 0, 0);
        }
    }

    if (EPI == 4) {
        __syncthreads();
        if (tid < 128) red[tid] = 0.f;
        __syncthreads();
        float b1c[4], w2c[4];
#pragma unroll
        for (int nt = 0; nt < 4; nt++) {
            int col = colblk * 128 + wc * 64 + nt * 16 + col_l;
            b1c[nt] = bias[col];
            w2c[nt] = w2[col];
        }
#pragma unroll
        for (int mt = 0; mt < 4; mt++) {
#pragma unroll
            for (int r = 0; r < 4; r++) {
                int lrow = wr * 64 + mt * 16 + quad * 4 + r;
                int e = p * 128 + lrow;
                int ec = e < M ? e : M - 1;
                int s = srcp[ec], d = dstp[ec];
                const float* hsr = Hs + (size_t)s * 256;
                const float* hdr = Hd + (size_t)d * 256;
                float part = 0.f;
#pragma unroll
                for (int nt = 0; nt < 4; nt++) {
                    int col = colblk * 128 + wc * 64 + nt * 16 + col_l;
                    part += fmaxf(acc[mt][nt][r] + hsr[col] + hdr[col] + b1c[nt], 0.f)
                            * w2c[nt];
                }
#pragma unroll
                for (int m = 8; m > 0; m >>= 1) part += __shfl_xor(part, m, 64);
                if (col_l == 0) atomicAdd(&red[lrow], part);
            }
        }
        __syncthreads();
        if (tid < 128) {
            int e = p * 128 + tid;
            if (e < M) {
                float* tgt = colblk ? (float*)out2 : (float*)out;
                tgt[e] = red[tid];
            }
        }
        return;
    }

    float bs[4];
    if (EPI >= 2) {
#pragma unroll
        for (int nt = 0; nt < 4; nt++)
            bs[nt] = bias[colblk * 128 + wc * 64 + nt * 16 + col_l];
    }
#pragma unroll
    for (int mt = 0; mt < 4; mt++) {
#pragma unroll
        for (int nt = 0; nt < 4; nt++) {
            int colg = colblk * 128 + wc * 64 + nt * 16 + col_l;
#pragma unroll
            for (int r = 0; r < 4; r++) {
                int rg = p * 128 + wr * 64 + mt * 16 + quad * 4 + r;
                if (rg < M) {
                    float v = acc[mt][nt][r];
                    if (EPI >= 2) v += bs[nt];
                    if (EPI == 3) v = fmaxf(v, 0.f);
                    if (EPI == 0)
                        ((float*)Osel)[(size_t)rg * rsOut + colg] = v;
                    else
                        ((ushort_t*)Osel)[(size_t)rg * rsOut + colg] = f2bf(v);
                }
            }
        }
    }
}

// ---------------------------------------------------------------------------
// Finalize pred head: logit = part0 + part1 + b2; sampled = sigmoid(logit+noise)
// ---------------------------------------------------------------------------
__global__ void finalize_kernel(float* __restrict__ out, const float* __restrict__ part1,
                                const float* __restrict__ b2v, float* __restrict__ out_s) {
    int e = blockIdx.x * blockDim.x + threadIdx.x;
    if (e >= NE) return;
    float logit = out[e] + part1[e] + b2v[0];
    out[e] = logit;
    unsigned y0, y1;
    threefry2x32(0u, 42u, 0u, (unsigned)e, y0, y1);
    unsigned bits = y0 ^ y1;
    float f = __uint_as_float((bits >> 9) | 0x3F800000u) - 1.0f;
    float u = fmaxf(1e-10f, f + 1e-10f);
    float noise = logf(u) - logf(1.0f - u);
    out_s[e] = 1.0f / (1.0f + expf(-(logit + noise)));
}

// ---------------------------------------------------------------------------
// Edge-attribute sum per node (shared across both SAGE layers), fp32.
// ---------------------------------------------------------------------------
__global__ __launch_bounds__(64) void agg_ea_kernel(
        const ushort_t* __restrict__ eaf, const ushort_t* __restrict__ ear,
        const int* __restrict__ row_start, const int* __restrict__ elist,
        float* __restrict__ agg_ea) {
    int n = blockIdx.x;
    int c = threadIdx.x * 4;
    float ax = 0.f, ay = 0.f, az = 0.f, aw = 0.f;
    int beg = row_start[n], end = row_start[n + 1];
    for (int p = beg; p < end; p++) {
        int i = elist[p];
        const ushort_t* er = (i < NE) ? eaf + (size_t)i * 256
                                      : ear + (size_t)(i - NE) * 256;
        ushort4 ev = *(const ushort4*)(er + c);
        ax += bf2f(ev.x); ay += bf2f(ev.y); az += bf2f(ev.z); aw += bf2f(ev.w);
    }
    float4 o; o.x = ax; o.y = ay; o.z = az; o.w = aw;
    *(float4*)(agg_ea + (size_t)n * 256 + c) = o;
}

// ---------------------------------------------------------------------------
// Node-feature mean aggregation: agg[n] = (sum x[srcnode] + agg_ea[n]) / deg.
// ---------------------------------------------------------------------------
__global__ __launch_bounds__(64) void agg_x_kernel(
        const ushort_t* __restrict__ xin, int rsx,
        const int* __restrict__ src, const int* __restrict__ dst,
        const int* __restrict__ row_start, const int* __restrict__ elist,
        const int* __restrict__ deg, const float* __restrict__ agg_ea,
        ushort_t* __restrict__ agg) {
    int n = blockIdx.x;
    int c = threadIdx.x * 4;
    float ax = 0.f, ay = 0.f, az = 0.f, aw = 0.f;
    int beg = row_start[n], end = row_start[n + 1];
    for (int p = beg; p < end; p++) {
        int i = elist[p];
        int node = (i < NE) ? src[i] : dst[i - NE];
        ushort4 xv = *(const ushort4*)(xin + (size_t)node * rsx + c);
        ax += bf2f(xv.x); ay += bf2f(xv.y); az += bf2f(xv.z); aw += bf2f(xv.w);
    }
    float4 e = *(const float4*)(agg_ea + (size_t)n * 256 + c);
    float d = fmaxf((float)deg[n], 1.0f);
    ushort4 o;
    o.x = f2bf((ax + e.x) / d); o.y = f2bf((ay + e.y) / d);
    o.z = f2bf((az + e.z) / d); o.w = f2bf((aw + e.w) / d);
    *(ushort4*)(agg + (size_t)n * 256 + c) = o;
}

// ---------------------------------------------------------------------------
extern "C" void kernel_launch(void* const* d_in, const int* in_sizes, int n_in,
                              void* d_out, int out_size, void* d_ws, size_t ws_size,
                              hipStream_t stream) {
    const float* x        = (const float*)d_in[0];
    const float* ea       = (const float*)d_in[1];
    const float* qemb     = (const float*)d_in[2];
    const int*   eidx     = (const int*)d_in[3];
    const float* W_rev1   = (const float*)d_in[4];
    const float* b_rev1   = (const float*)d_in[5];
    const float* W_rev2   = (const float*)d_in[6];
    const float* b_rev2   = (const float*)d_in[7];
    const float* W_sage1  = (const float*)d_in[8];
    const float* b_sage1  = (const float*)d_in[9];
    const float* W_sage2  = (const float*)d_in[10];
    const float* b_sage2  = (const float*)d_in[11];
    const float* W_pred1  = (const float*)d_in[12];
    const float* b_pred1  = (const float*)d_in[13];
    const float* W_pred2  = (const float*)d_in[14];
    const float* b_pred2  = (const float*)d_in[15];
    float* out = (float*)d_out;

    const int* src = eidx;
    const int* dst = eidx + NE;

    // ---- workspace layout ----
    char* w = (char*)d_ws;
    ushort_t* ea_bf  = (ushort_t*)w; w += (size_t)NE * 256 * 2;   // 102.4 MB
    ushort_t* ea_rev_bf = (ushort_t*)w; w += (size_t)NE * 256 * 2;// 102.4 MB
    ushort_t* x_bf   = (ushort_t*)w; w += (size_t)NN * 256 * 2;
    ushort_t* H      = (ushort_t*)w; w += (size_t)NN * 512 * 2;   // [h1|h2]
    ushort_t* agg_bf = (ushort_t*)w; w += (size_t)NN * 256 * 2;
    float*    Hsrc   = (float*)w;    w += (size_t)NN * 256 * 4;   // also agg_ea
    float*    Hdst   = (float*)w;    w += (size_t)NN * 256 * 4;
    float*    part1  = (float*)w;    w += (size_t)NE * 4;
    ushort_t* Wt_rev1  = (ushort_t*)w; w += 256 * 256 * 2;
    ushort_t* Wt_rev2  = (ushort_t*)w; w += 256 * 256 * 2;
    ushort_t* Wt_sage1 = (ushort_t*)w; w += 256 * 512 * 2;
    ushort_t* Wt_sage2 = (ushort_t*)w; w += 256 * 512 * 2;
    ushort_t* Wt_src   = (ushort_t*)w; w += 256 * 512 * 2;
    ushort_t* Wt_dst   = (ushort_t*)w; w += 256 * 512 * 2;
    ushort_t* Wt_edge  = (ushort_t*)w; w += 256 * 512 * 2;
    int* deg       = (int*)w; w += (size_t)NN * 4;
    int* row_start = (int*)w; w += (size_t)(NN + 1) * 4;
    int* cursor    = (int*)w; w += (size_t)NN * 4;
    int* elist     = (int*)w; w += (size_t)NE2 * 4;

    float* agg_ea = Hsrc;   // alias: agg_ea dead before Hsrc written (pair GEMM)

    const int EB = (NE + 127) / 128;   // 1563 row-blocks
    const int NB = (NN + 127) / 128;   // 157 row-blocks

    // ---- CSR ----
    hipMemsetAsync(deg, 0, (size_t)NN * 4, stream);
    deg_kernel<<<(NE2 + 255) / 256, 256, 0, stream>>>(src, dst, deg);
    prefix_kernel<<<1, 1024, 0, stream>>>(deg, row_start, cursor);
    scatter_kernel<<<(NE2 + 255) / 256, 256, 0, stream>>>(src, dst, cursor, elist);

    // ---- all weight transposes, one launch ----
    TA ta;
    ta.d[0] = { W_rev1,  Wt_rev1,  256, 0,   256 };
    ta.d[1] = { W_rev2,  Wt_rev2,  256, 0,   256 };
    ta.d[2] = { W_sage1, Wt_sage1, 512, 0,   512 };
    ta.d[3] = { W_sage2, Wt_sage2, 512, 0,   512 };
    ta.d[4] = { W_pred1 + (size_t)256 * 256,  Wt_src,  512, 0,   512 };
    ta.d[5] = { W_pred1 + (size_t)1024 * 256, Wt_dst,  512, 0,   512 };
    ta.d[6] = { W_pred1,                      Wt_edge, 512, 0,   256 };
    ta.d[7] = { W_pred1 + (size_t)768 * 256,  Wt_edge, 512, 256, 256 };
    transpose_all_kernel<<<dim3(512, 8), 256, 0, stream>>>(ta);

    // ---- activations to bf16 (ea + x, one launch) ----
    conv2_kernel<<<((NE + NN) * 32 + 255) / 256, 256, 0, stream>>>(
        ea, ea_bf, NE * 32, x, x_bf, NN * 32);

    // ---- fused reverse-edge MLP (lean: no spill, h in LDS only) ----
    rev_fused_kernel<<<NE / 64, 256, 0, stream>>>(
        ea_bf, Wt_rev1, b_rev1, Wt_rev2, b_rev2, ea_rev_bf);

    // ---- shared edge-attr aggregation (once for both SAGE layers) ----
    agg_ea_kernel<<<NN, 64, 0, stream>>>(ea_bf, ea_rev_bf, row_start, elist, agg_ea);

    // ---- SAGE layer 1 ----
    agg_x_kernel<<<NN, 64, 0, stream>>>(x_bf, 256, src, dst, row_start, elist,
                                        deg, agg_ea, agg_bf);
    mfma_gemm<512, 3, false><<<NB * 2, 256, 0, stream>>>(
        x_bf, 256, agg_bf, 256, Wt_sage1, nullptr, b_sage1,
        H, nullptr, 512, NN, nullptr, nullptr, nullptr, nullptr, nullptr);

    // ---- SAGE layer 2 ----
    agg_x_kernel<<<NN, 64, 0, stream>>>(H, 512, src, dst, row_start, elist,
                                        deg, agg_ea, agg_bf);
    mfma_gemm<512, 3, false><<<NB * 2, 256, 0, stream>>>(
        H, 512, agg_bf, 256, Wt_sage2, nullptr, b_sage2,
        H + 256, nullptr, 512, NN, nullptr, nullptr, nullptr, nullptr, nullptr);

    // ---- node-side pred contributions: Hsrc & Hdst in one paired launch ----
    mfma_gemm<512, 0, false><<<dim3(NB * 2, 2), 256, 0, stream>>>(
        H, 512, H + 256, 512, Wt_src, Wt_dst, nullptr,
        Hsrc, Hdst, 256, NN, nullptr, nullptr, nullptr, nullptr, nullptr);

    // ---- edge GEMM + fused pred head partials (q read fp32, cvt in staging) ----
    mfma_gemm<512, 4, true><<<EB * 2, 256, 0, stream>>>(
        qemb, 256, ea_bf, 256, Wt_edge, nullptr, b_pred1,
        out, part1, 0, NE, src, dst, Hsrc, Hdst, W_pred2);

    // ---- finalize: add halves + b2, threefry noise, sigmoid ----
    finalize_kernel<<<(NE + 255) / 256, 256, 0, stream>>>(out, part1, b_pred2, out + NE);
}